// Round 3
// baseline (574.867 us; speedup 1.0000x reference)
//
#include <hip/hip_runtime.h>
#include <hip/hip_bf16.h>
#include <hip/hip_fp8.h>
#include <math.h>

// Problem constants (fixed by setup_inputs): B=4096, D=512, V=50000.
#define B_ROWS 4096
#define DIMS   512
#define V_ROWS 50000
#define V_PAD  50048            // 391 * 128
#define NTILES 391              // V_PAD / 128
#define NT_PAD 392              // cands row stride (ulonglong2 units)
#define MTILES 32               // B_ROWS / 128
#define NROWS_ALL 54144         // V_PAD + B_ROWS (fused normalize grid-stride range)
#define EPSF   1e-8f
#define QSCALE 64.0f            // row pre-scale before fp8 quant (dodges e4m3 subnormals)
#define SCALE1 0x7F7F7F7F       // E8M0 unity scale broadcast to all 4 bytes

typedef float f32x4 __attribute__((ext_vector_type(4)));
typedef int   i32x4 __attribute__((ext_vector_type(4)));
typedef int   i32x8 __attribute__((ext_vector_type(8)));
typedef unsigned long long u64;

// fp8 e4m3 (OCP) pack of 4 floats -> u32, bytes little-endian in k order
__device__ __forceinline__ unsigned int pk4_fp8(float a, float b, float c, float d) {
#if __has_builtin(__builtin_amdgcn_cvt_pk_fp8_f32)
  int w = __builtin_amdgcn_cvt_pk_fp8_f32(a, b, 0, false);   // bytes 0,1
  w = __builtin_amdgcn_cvt_pk_fp8_f32(c, d, w, true);        // bytes 2,3
  return (unsigned int)w;
#else
  __hip_fp8_e4m3 qa(a), qb(b), qc(c), qd(d);
  return (unsigned int)qa.__x | ((unsigned int)qb.__x << 8) |
         ((unsigned int)qc.__x << 16) | ((unsigned int)qd.__x << 24);
#endif
}

// ---------------------------------------------------------------------------
// Packed top-2 keys. key = (sortable(v) << 32) | ~col.
// u64 compare == (value desc, col asc) — matches jax top_k first-occurrence
// tie-break exactly. Keys within a row are always distinct (distinct cols).
// ---------------------------------------------------------------------------
__device__ __forceinline__ u64 pack_key(float v, int col) {
  unsigned int u = __float_as_uint(v);
  unsigned int s = u ^ ((unsigned int)((int)u >> 31) | 0x80000000u);
  return ((u64)s << 32) | (unsigned int)(~col);
}
__device__ __forceinline__ int key_col(u64 k) {
  return (int)(~(unsigned int)k);
}
// merge sorted pair (a0>=a1) into running sorted top-2 (k0>=k1)
__device__ __forceinline__ void kmerge(u64& k0, u64& k1, u64 a0, u64 a1) {
  bool bt = a0 > k0;
  u64 lo = bt ? k0 : a0;        // loser of the top comparison
  u64 hi = bt ? a1 : k1;        // runner-up of the winner's pair
  k0 = bt ? a0 : k0;
  k1 = hi > lo ? hi : lo;
}

// ---------------------------------------------------------------------------
// K1 (fused): row-normalize fp32 -> fp8 e4m3 (scaled by QSCALE) for BOTH
// veclist (rows [0,V_PAD), pad rows zero-filled) and input (rows
// [V_PAD, V_PAD+B_ROWS)). One WAVE per row (64 lanes x 8 elems), grid-stride.
// ---------------------------------------------------------------------------
__global__ __launch_bounds__(256)
void normalize_rows_kernel(const float* __restrict__ vsrc, const float* __restrict__ isrc,
                           unsigned char* __restrict__ vdst, unsigned char* __restrict__ idst) {
  const int l = threadIdx.x & 63;
  const int gw = (blockIdx.x * 256 + threadIdx.x) >> 6;
  const int nw = (gridDim.x * 256) >> 6;
  for (int row = gw; row < NROWS_ALL; row += nw) {
    const float* src;
    unsigned char* dst;
    if (row < V_PAD) {
      if (row >= V_ROWS) {           // zero-fill pad rows
        *(uint2*)&vdst[(size_t)row * DIMS + l * 8] = make_uint2(0u, 0u);
        continue;
      }
      src = vsrc + (size_t)row * DIMS;
      dst = vdst + (size_t)row * DIMS;
    } else {
      src = isrc + (size_t)(row - V_PAD) * DIMS;
      dst = idst + (size_t)(row - V_PAD) * DIMS;
    }
    float4 v0 = ((const float4*)src)[l * 2];
    float4 v1 = ((const float4*)src)[l * 2 + 1];
    float ss = v0.x * v0.x + v0.y * v0.y + v0.z * v0.z + v0.w * v0.w
             + v1.x * v1.x + v1.y * v1.y + v1.z * v1.z + v1.w * v1.w;
    #pragma unroll
    for (int d = 1; d < 64; d <<= 1) ss += __shfl_xor(ss, d);
    float s = QSCALE / fmaxf(sqrtf(ss), EPSF);
    uint2 o;
    o.x = pk4_fp8(v0.x * s, v0.y * s, v0.z * s, v0.w * s);
    o.y = pk4_fp8(v1.x * s, v1.y * s, v1.z * s, v1.w * s);
    *(uint2*)&dst[l * 8] = o;
  }
}

// ---------------------------------------------------------------------------
// K3: MX-scaled fp8 MFMA GEMM — LDS-FREE K-loop this round (r9).
// r8 post-mortem: pipeline@2blk == drain@2.6blk => neither vmcnt drains nor
// occupancy was the binding limit. Resource audit: LDS pipe ~55-60% busy
// (256 ds_read_b128 + 128KB global_load_lds writes + 1.6e7 conflict cy) =
// the most-utilized resource. Fix: drop LDS staging entirely.
//   Each lane loads its MFMA fragments DIRECTLY from global as 2 contiguous
//   dwordx4: lane (lr,lq), half c reads bytes [k0 + c*64 + lq*16, +16) of
//   its row. This is a different k->(reg,byte) mapping than the old LDS
//   path, but it is applied IDENTICALLY to A and B, so the contraction
//   pairs the same a_j*b_j products (prior session verified mapping-
//   invariance, absmax 0). All 64 loads fold to 8 base pointers + 13-bit
//   imm offsets (k0 + c*64 <= 448): K-loop VALU ~ zero, NO barriers,
//   NO LDS in the K-loop. A-tiles are XCD-L2-resident (mt = bid&31 pins
//   mt to one XCD); B-tiles L1/L2-hot; waves fully independent.
// LDS = 32KB epilogue scratch only. Epilogue byte-identical to r7-verified.
// ---------------------------------------------------------------------------
__global__ __launch_bounds__(256, 2)
void gemm_top2_kernel(const unsigned char* __restrict__ A8,
                      const unsigned char* __restrict__ B8,
                      ulonglong2* __restrict__ cands) {
  __shared__ __align__(16) ulonglong2 ep[64][32];   // 32 KB epilogue scratch

  const int bid = blockIdx.x;
  const int mt = bid & 31;        // 32 consecutive blocks share the B-tile
  const int nt = bid >> 5;        // 0..390
  const int m0 = mt * 128, n0 = nt * 128;

  const int tid = threadIdx.x;
  const int w = tid >> 6, l = tid & 63;
  const int wr = w >> 1, wc = w & 1;     // 2x2 wave grid, 64x64 per wave
  const int lq = l >> 4, lr = l & 15;

  // per-lane fragment base pointers: row-major rows, + lq*16 within window
  const unsigned char* abase[4];
  const unsigned char* bbase[4];
  #pragma unroll
  for (int tr = 0; tr < 4; ++tr)
    abase[tr] = A8 + (size_t)(m0 + wr * 64 + tr * 16 + lr) * DIMS + lq * 16;
  #pragma unroll
  for (int tc = 0; tc < 4; ++tc)
    bbase[tc] = B8 + (size_t)(n0 + wc * 64 + tc * 16 + lr) * DIMS + lq * 16;

  f32x4 acc[4][4] = {};

  #pragma unroll
  for (int k0 = 0; k0 < DIMS; k0 += 128) {
    // B fragments for all 4 col-tiles (32 VGPRs live)
    i32x8 bf[4];
    #pragma unroll
    for (int tc = 0; tc < 4; ++tc) {
      i32x4 blo = *(const i32x4*)(bbase[tc] + k0);        // half c=0
      i32x4 bhi = *(const i32x4*)(bbase[tc] + k0 + 64);   // half c=1
      bf[tc] = __builtin_shufflevector(blo, bhi, 0, 1, 2, 3, 4, 5, 6, 7);
    }
    // A fragments one row-tile at a time; 4 MFMAs each
    #pragma unroll
    for (int tr = 0; tr < 4; ++tr) {
      i32x4 alo = *(const i32x4*)(abase[tr] + k0);
      i32x4 ahi = *(const i32x4*)(abase[tr] + k0 + 64);
      i32x8 af = __builtin_shufflevector(alo, ahi, 0, 1, 2, 3, 4, 5, 6, 7);
      #pragma unroll
      for (int tc = 0; tc < 4; ++tc)
        acc[tr][tc] = __builtin_amdgcn_mfma_scale_f32_16x16x128_f8f6f4(
            af, bf[tc], acc[tr][tc],
            0, 0,                 // cbsz = fp8(e4m3), blgp = fp8(e4m3)
            0, SCALE1,            // scale_a opsel, scale_a (unity all bytes)
            0, SCALE1);           // scale_b opsel, scale_b
    }
  }

  // ---- epilogue: per-row top-2 over this block's 128 cols (packed u64) ----
  // C/D layout: row = (lane>>4)*4 + reg, col = lane&15 (per 16x16 tile).
  // ep: 64 slots x 32 entries x 16 B = 32 KB.
  // slot = wr*32 + trh*16 + lq*4 + reg  ->  row = (slot>>5)*64 + p*32 + (slot&31)
  const int colbase = n0 + wc * 64 + lr;

  #pragma unroll
  for (int p = 0; p < 2; ++p) {
    #pragma unroll
    for (int trh = 0; trh < 2; ++trh) {
      const int tr = p * 2 + trh;
      #pragma unroll
      for (int rg = 0; rg < 4; ++rg) {
        u64 kk[4];
        #pragma unroll
        for (int tc = 0; tc < 4; ++tc) {
          const int col = colbase + tc * 16;
          const float v = (col < V_ROWS) ? acc[tr][tc][rg] : -INFINITY;  // pad-col mask
          kk[tc] = pack_key(v, col);
        }
        const bool s01 = kk[0] > kk[1];
        u64 a0 = s01 ? kk[0] : kk[1], a1 = s01 ? kk[1] : kk[0];
        const bool s23 = kk[2] > kk[3];
        u64 b0 = s23 ? kk[2] : kk[3], b1 = s23 ? kk[3] : kk[2];
        kmerge(a0, a1, b0, b1);                       // sorted top-2 of 4 tc
        const int slot = wr * 32 + trh * 16 + lq * 4 + rg;
        ep[slot][(wc * 16 + lr) ^ (slot & 7)] = make_ulonglong2(a0, a1);
      }
    }
    __syncthreads();
    {
      // 4 threads per row merge 8 sorted pairs each, then quad-combine.
      const int ms = tid >> 2, q = tid & 3;
      u64 k0 = 0, k1 = 0;                             // 0 < any real key
      #pragma unroll
      for (int k = 0; k < 8; ++k) {
        ulonglong2 e = ep[ms][(q * 8 + k) ^ (ms & 7)];
        kmerge(k0, k1, e.x, e.y);
      }
      #pragma unroll
      for (int d = 1; d < 4; d <<= 1) {
        u64 o0 = __shfl_xor(k0, d), o1 = __shfl_xor(k1, d);
        kmerge(k0, k1, o0, o1);
      }
      if (q == 0) {
        const int row = (ms >> 5) * 64 + p * 32 + (ms & 31);
        // transposed layout: [row][tile] so finalize reads are coalesced
        cands[(size_t)(m0 + row) * NT_PAD + nt] = make_ulonglong2(k0, k1);
      }
    }
    __syncthreads();   // LDS reused by next pass
  }
}

// ---------------------------------------------------------------------------
// K5: per-row final. Merge 391 packed tile candidate pairs -> global top-2
// indices (u64 compares only; values never unpacked), then recompute
// d_pos / d_neg exactly in fp32 from the original inputs. Per-row contrib,
// no single-address atomics.
// ---------------------------------------------------------------------------
__global__ __launch_bounds__(256)
void finalize_kernel(const float* __restrict__ input, const float* __restrict__ target,
                     const float* __restrict__ veclist, const ulonglong2* __restrict__ cands,
                     float* __restrict__ contrib) {
  const int b = blockIdx.x;
  const int t = threadIdx.x;
  __shared__ ulonglong2 wpair[4];
  __shared__ int sidx[2];
  __shared__ float red[4][7];
  __shared__ int reda[4];

  // phase A: global top-2 across tiles (coalesced: cands[b][nt])
  u64 k0 = 0, k1 = 0;
  for (int nt = t; nt < NTILES; nt += 256) {
    ulonglong2 c = cands[(size_t)b * NT_PAD + nt];
    kmerge(k0, k1, c.x, c.y);
  }
  #pragma unroll
  for (int d = 1; d < 64; d <<= 1) {
    u64 o0 = __shfl_xor(k0, d), o1 = __shfl_xor(k1, d);
    kmerge(k0, k1, o0, o1);
  }
  if ((t & 63) == 0) wpair[t >> 6] = make_ulonglong2(k0, k1);
  __syncthreads();
  if (t == 0) {
    u64 m0k = wpair[0].x, m1k = wpair[0].y;
    for (int wd = 1; wd < 4; ++wd) kmerge(m0k, m1k, wpair[wd].x, wpair[wd].y);
    sidx[0] = key_col(m0k);
    sidx[1] = key_col(m1k);
  }
  __syncthreads();
  const int idx0 = sidx[0], idx1 = sidx[1];

  // phase B: exact fp32 dot products / norms
  const float2* xin = (const float2*)(input  + (size_t)b * DIMS);
  const float2* xtg = (const float2*)(target + (size_t)b * DIMS);
  const float2* xv0 = (const float2*)(veclist + (size_t)idx0 * DIMS);
  const float2* xv1 = (const float2*)(veclist + (size_t)idx1 * DIMS);
  float2 xi = xin[t], tg = xtg[t], a0 = xv0[t], a1 = xv1[t];
  float s[7];
  s[0] = xi.x * xi.x + xi.y * xi.y;
  s[1] = tg.x * tg.x + tg.y * tg.y;
  s[2] = xi.x * tg.x + xi.y * tg.y;
  s[3] = a0.x * a0.x + a0.y * a0.y;
  s[4] = xi.x * a0.x + xi.y * a0.y;
  s[5] = a1.x * a1.x + a1.y * a1.y;
  s[6] = xi.x * a1.x + xi.y * a1.y;
  bool eq = (a0.x == tg.x) && (a0.y == tg.y);
  int weq = __all(eq);
  #pragma unroll
  for (int k = 0; k < 7; ++k)
    #pragma unroll
    for (int d = 1; d < 64; d <<= 1) s[k] += __shfl_xor(s[k], d);
  if ((t & 63) == 0) {
    #pragma unroll
    for (int k = 0; k < 7; ++k) red[t >> 6][k] = s[k];
    reda[t >> 6] = weq;
  }
  __syncthreads();
  if (t == 0) {
    float r[7];
    #pragma unroll
    for (int k = 0; k < 7; ++k)
      r[k] = red[0][k] + red[1][k] + red[2][k] + red[3][k];
    bool eq0 = reda[0] && reda[1] && reda[2] && reda[3];
    float na  = fmaxf(sqrtf(r[0]), EPSF);
    float ntg = fmaxf(sqrtf(r[1]), EPSF);
    float simp = r[2] / (na * ntg);
    float d_pos = sqrtf(fmaxf(2.0f * (1.0f - simp), 1e-12f));
    float nn = eq0 ? fmaxf(sqrtf(r[5]), EPSF) : fmaxf(sqrtf(r[3]), EPSF);
    float dn = eq0 ? r[6] : r[4];
    float simn = dn / (na * nn);
    float d_neg = sqrtf(fmaxf(2.0f * (1.0f - simn), 1e-12f));
    float margin = 0.5f + d_pos - d_neg;          // GAMMA + d_pos - d_neg
    contrib[b] = 2.0f * fmaxf(margin, 0.0f) * (1.0f / (float)B_ROWS);  // RANK=2
  }
}

// ---------------------------------------------------------------------------
// K6: sum 4096 per-row contributions -> out[0]. One block, no atomics.
// ---------------------------------------------------------------------------
__global__ __launch_bounds__(256)
void reduce_kernel(const float* __restrict__ contrib, float* __restrict__ out) {
  const int t = threadIdx.x;
  __shared__ float wsum[4];
  float s = 0.0f;
  for (int i = t; i < B_ROWS; i += 256) s += contrib[i];
  #pragma unroll
  for (int d = 1; d < 64; d <<= 1) s += __shfl_xor(s, d);
  if ((t & 63) == 0) wsum[t >> 6] = s;
  __syncthreads();
  if (t == 0) out[0] = wsum[0] + wsum[1] + wsum[2] + wsum[3];
}

// ---------------------------------------------------------------------------
// Workspace layout (bytes):
//   vnn  fp8 [50048][512]          @ 0          : 25,624,576
//   inn  fp8 [4096][512]           @ 25,624,576 :  2,097,152
//   cands ulonglong2 [4096][392]   @ 27,721,728 : 25,690,112
//   contrib float [4096]           @ 53,411,840 :     16,384   (total ~53.4 MB)
// ---------------------------------------------------------------------------
extern "C" void kernel_launch(void* const* d_in, const int* in_sizes, int n_in,
                              void* d_out, int out_size, void* d_ws, size_t ws_size,
                              hipStream_t stream) {
  const float* input   = (const float*)d_in[0];
  const float* target  = (const float*)d_in[1];
  const float* veclist = (const float*)d_in[2];
  float* out = (float*)d_out;
  char* ws = (char*)d_ws;
  unsigned char* vnn = (unsigned char*)ws;
  unsigned char* inn = (unsigned char*)(ws + 25624576);
  ulonglong2* cands = (ulonglong2*)(ws + 27721728);
  float* contrib = (float*)(ws + 53411840);

  normalize_rows_kernel<<<4096, 256, 0, stream>>>(veclist, input, vnn, inn);
  gemm_top2_kernel<<<MTILES * NTILES, 256, 0, stream>>>(inn, vnn, cands);
  finalize_kernel<<<B_ROWS, 256, 0, stream>>>(input, target, veclist, cands, contrib);
  reduce_kernel<<<1, 256, 0, stream>>>(contrib, out);
}

// Round 4
// 362.490 us; speedup vs baseline: 1.5859x; 1.5859x over previous
//
#include <hip/hip_runtime.h>
#include <hip/hip_bf16.h>
#include <hip/hip_fp8.h>
#include <math.h>

// Problem constants (fixed by setup_inputs): B=4096, D=512, V=50000.
#define B_ROWS 4096
#define DIMS   512
#define V_ROWS 50000
#define V_PAD  50048            // 391 * 128
#define NTILES 391              // V_PAD / 128
#define NT_PAD 392              // cands row stride (ulonglong2 units)
#define MTILES 32               // B_ROWS / 128
#define NROWS_ALL 54144         // V_PAD + B_ROWS (fused normalize grid-stride range)
#define EPSF   1e-8f
#define QSCALE 64.0f            // row pre-scale before fp8 quant (dodges e4m3 subnormals)
#define SCALE1 0x7F7F7F7F       // E8M0 unity scale broadcast to all 4 bytes

typedef float f32x4 __attribute__((ext_vector_type(4)));
typedef int   i32x4 __attribute__((ext_vector_type(4)));
typedef int   i32x8 __attribute__((ext_vector_type(8)));
typedef unsigned long long u64;

// fp8 e4m3 (OCP) pack of 4 floats -> u32, bytes little-endian in k order
__device__ __forceinline__ unsigned int pk4_fp8(float a, float b, float c, float d) {
#if __has_builtin(__builtin_amdgcn_cvt_pk_fp8_f32)
  int w = __builtin_amdgcn_cvt_pk_fp8_f32(a, b, 0, false);   // bytes 0,1
  w = __builtin_amdgcn_cvt_pk_fp8_f32(c, d, w, true);        // bytes 2,3
  return (unsigned int)w;
#else
  __hip_fp8_e4m3 qa(a), qb(b), qc(c), qd(d);
  return (unsigned int)qa.__x | ((unsigned int)qb.__x << 8) |
         ((unsigned int)qc.__x << 16) | ((unsigned int)qd.__x << 24);
#endif
}

// async global->LDS, 16B per lane. LDS dest is wave-uniform base + lane*16.
__device__ __forceinline__ void lds_load16(const void* g, void* l) {
  __builtin_amdgcn_global_load_lds(
      (const __attribute__((address_space(1))) void*)g,
      (__attribute__((address_space(3))) void*)l, 16, 0, 0);
}

// ---------------------------------------------------------------------------
// Packed top-2 keys. key = (sortable(v) << 32) | ~col.
// u64 compare == (value desc, col asc) — matches jax top_k first-occurrence
// tie-break exactly. Keys within a row are always distinct (distinct cols).
// ---------------------------------------------------------------------------
__device__ __forceinline__ u64 pack_key(float v, int col) {
  unsigned int u = __float_as_uint(v);
  unsigned int s = u ^ ((unsigned int)((int)u >> 31) | 0x80000000u);
  return ((u64)s << 32) | (unsigned int)(~col);
}
__device__ __forceinline__ int key_col(u64 k) {
  return (int)(~(unsigned int)k);
}
// merge sorted pair (a0>=a1) into running sorted top-2 (k0>=k1)
__device__ __forceinline__ void kmerge(u64& k0, u64& k1, u64 a0, u64 a1) {
  bool bt = a0 > k0;
  u64 lo = bt ? k0 : a0;        // loser of the top comparison
  u64 hi = bt ? a1 : k1;        // runner-up of the winner's pair
  k0 = bt ? a0 : k0;
  k1 = hi > lo ? hi : lo;
}

// ---------------------------------------------------------------------------
// K1 (fused): row-normalize fp32 -> fp8 e4m3 (scaled by QSCALE).
//   veclist rows [0,V_PAD): row-major fp8 (pad rows zero-filled) — GEMM
//     B-operand, staged through LDS.
//   input rows [V_PAD,..): written in PACKED A-FRAGMENT layout (r10):
//     record(mt,wr,ks,tr,half) = 1KB = 64 lane-slots x 16B, where the GEMM
//     lane l=(lq*16+lr) of wave-row wr reads slot l of record (ks,tr,half)
//     as bytes k=[128ks+32lq+16half, +16) of A-row m0+wr*64+tr*16+lr.
//     This makes A-fragment loads wave-contiguous 1KB dwordx4 (no LDS
//     round-trip, no 16-line split — fixes r9's latency collapse).
//     Same linear k-map as the B LDS path (XOR swizzle cancels), so the
//     A/B mapping-consistency invariant (absmax 0) is preserved.
//   Writer-side decode for row m, lane l holding bytes [8l, 8l+8):
//     ks=l>>4, lq=(l>>2)&3, half=(l>>1)&1, byte=(l&1)*8;
//     rec = ((((m>>7)*2 + ((m>>6)&1))*4 + ks)*4 + ((m>>4)&3))*2 + half
//     off = rec*1024 + (lq*16 + (m&15))*16 + (l&1)*8   (8B uint2 store)
// ---------------------------------------------------------------------------
__global__ __launch_bounds__(256)
void normalize_rows_kernel(const float* __restrict__ vsrc, const float* __restrict__ isrc,
                           unsigned char* __restrict__ vdst, unsigned char* __restrict__ apk) {
  const int l = threadIdx.x & 63;
  const int gw = (blockIdx.x * 256 + threadIdx.x) >> 6;
  const int nw = (gridDim.x * 256) >> 6;
  for (int row = gw; row < NROWS_ALL; row += nw) {
    const float* src;
    if (row < V_PAD) {
      if (row >= V_ROWS) {           // zero-fill pad rows
        *(uint2*)&vdst[(size_t)row * DIMS + l * 8] = make_uint2(0u, 0u);
        continue;
      }
      src = vsrc + (size_t)row * DIMS;
    } else {
      src = isrc + (size_t)(row - V_PAD) * DIMS;
    }
    float4 v0 = ((const float4*)src)[l * 2];
    float4 v1 = ((const float4*)src)[l * 2 + 1];
    float ss = v0.x * v0.x + v0.y * v0.y + v0.z * v0.z + v0.w * v0.w
             + v1.x * v1.x + v1.y * v1.y + v1.z * v1.z + v1.w * v1.w;
    #pragma unroll
    for (int d = 1; d < 64; d <<= 1) ss += __shfl_xor(ss, d);
    float s = QSCALE / fmaxf(sqrtf(ss), EPSF);
    uint2 o;
    o.x = pk4_fp8(v0.x * s, v0.y * s, v0.z * s, v0.w * s);
    o.y = pk4_fp8(v1.x * s, v1.y * s, v1.z * s, v1.w * s);
    if (row < V_PAD) {
      *(uint2*)&vdst[(size_t)row * DIMS + l * 8] = o;
    } else {
      const int m = row - V_PAD;
      const int rec = (((( (m >> 7) * 2 + ((m >> 6) & 1) ) * 4 + (l >> 4)) * 4
                        + ((m >> 4) & 3)) * 2 + ((l >> 1) & 1));
      const int off = rec * 1024 + (((l >> 2) & 3) * 16 + (m & 15)) * 16 + (l & 1) * 8;
      *(uint2*)&apk[off] = o;
    }
  }
}

// ---------------------------------------------------------------------------
// K3: MX-scaled fp8 MFMA GEMM (mfma_scale_f32_16x16x128_f8f6f4, unity E8M0).
// r10: r7's verified 2-barrier schedule restored BYTE-IDENTICAL for the
// B path (stage->sync->ds_read->MFMA->sync), but A comes DIRECT from the
// packed-global layout written by normalize: per (ks,tr,half) one
// wave-contiguous 1KB dwordx4 load at Abase + l*16. A-loads issue alongside
// B staging; the existing __syncthreads vmcnt(0) drain doubles as their
// completion wait (zero extra sync).
//   vs r7: ds_read volume halved (A-side gone), staged bytes halved
//   (16KB/step), LDS = 16KB stage + 32KB epilogue = 48KB -> still 3
//   blocks/CU at the (256,3) reg cap (~100 VGPR + 64 AGPR).
//   vs r9 (417us latency collapse): A loads are wave-contiguous 1KB, not
//   16-line splits — full VMEM rate.
// Epilogue (packed-u64 top-2) byte-identical to the r7-verified version,
// now in its own 32KB scratch (no overlay hazard; loop ends with sync).
// ---------------------------------------------------------------------------
__global__ __launch_bounds__(256, 3)
void gemm_top2_kernel(const unsigned char* __restrict__ Apk,
                      const unsigned char* __restrict__ B8,
                      ulonglong2* __restrict__ cands) {
  __shared__ __align__(16) unsigned char Bs[128 * 128];   // 16 KB B stage
  __shared__ __align__(16) ulonglong2 ep[64][32];         // 32 KB epilogue

  const int bid = blockIdx.x;
  const int mt = bid & 31;        // 32 consecutive blocks share the B-tile
  const int nt = bid >> 5;        // 0..390
  const int m0 = mt * 128, n0 = nt * 128;

  const int tid = threadIdx.x;
  const int w = tid >> 6, l = tid & 63;
  const int wr = w >> 1, wc = w & 1;     // 2x2 wave grid, 64x64 per wave
  const int lq = l >> 4, lr = l & 15;
  const int h = lr & 7;                  // XOR swizzle key (B path)

  // B fragment slot offsets (constant across k0) — byte-identical to r7
  const int s0 = ((2 * lq) ^ h) * 16;    // byte offset of chunk 2lq
  const int s1 = ((2 * lq + 1) ^ h) * 16;

  // packed-A base for this thread: record block (mt,wr), lane slot l
  const unsigned char* const Abase =
      Apk + (size_t)(mt * 2 + wr) * 32768 + l * 16;

  f32x4 acc[4][4] = {};

  for (int ks = 0; ks < 4; ++ks) {
    // stage B fp8 tile: 1024 16B-chunks (128 rows x 8 chunks), XOR-8 swizzle
    #pragma unroll
    for (int it = 0; it < 4; ++it) {
      const int chunk = it * 256 + w * 64 + l;   // 0..1023
      const int row = chunk >> 3, c = chunk & 7;
      const int gc = c ^ (row & 7);              // swizzled global chunk
      lds_load16(B8 + (size_t)(n0 + row) * DIMS + ks * 128 + gc * 16,
                 &Bs[(it * 256 + w * 64) * 16]);
    }
    // A fragments direct from packed global (8 x wave-contiguous dwordx4);
    // the __syncthreads drain below completes them exactly when needed.
    i32x4 areg[4][2];
    #pragma unroll
    for (int tr = 0; tr < 4; ++tr) {
      areg[tr][0] = *(const i32x4*)(Abase + ks * 8192 + tr * 2048);
      areg[tr][1] = *(const i32x4*)(Abase + ks * 8192 + tr * 2048 + 1024);
    }
    __syncthreads();

    // B fragments for all 4 col-tiles (32 VGPRs live) — byte-identical r7
    i32x8 bf[4];
    #pragma unroll
    for (int tc = 0; tc < 4; ++tc) {
      const int rb = (wc * 64 + tc * 16 + lr) * 128;
      i32x4 blo = *(const i32x4*)&Bs[rb + s0];
      i32x4 bhi = *(const i32x4*)&Bs[rb + s1];
      bf[tc] = __builtin_shufflevector(blo, bhi, 0, 1, 2, 3, 4, 5, 6, 7);
    }
    // A fragments one row-tile at a time; 4 MFMAs each
    #pragma unroll
    for (int tr = 0; tr < 4; ++tr) {
      i32x8 af = __builtin_shufflevector(areg[tr][0], areg[tr][1],
                                         0, 1, 2, 3, 4, 5, 6, 7);
      #pragma unroll
      for (int tc = 0; tc < 4; ++tc)
        acc[tr][tc] = __builtin_amdgcn_mfma_scale_f32_16x16x128_f8f6f4(
            af, bf[tc], acc[tr][tc],
            0, 0,                 // cbsz = fp8(e4m3), blgp = fp8(e4m3)
            0, SCALE1,            // scale_a opsel, scale_a (unity all bytes)
            0, SCALE1);           // scale_b opsel, scale_b
    }
    __syncthreads();
  }

  // ---- epilogue: per-row top-2 over this block's 128 cols (packed u64) ----
  // C/D layout: row = (lane>>4)*4 + reg, col = lane&15 (per 16x16 tile).
  // ep: 64 slots x 32 entries x 16 B = 32 KB (dedicated scratch).
  // slot = wr*32 + trh*16 + lq*4 + reg  ->  row = (slot>>5)*64 + p*32 + (slot&31)
  const int colbase = n0 + wc * 64 + lr;

  #pragma unroll
  for (int p = 0; p < 2; ++p) {
    #pragma unroll
    for (int trh = 0; trh < 2; ++trh) {
      const int tr = p * 2 + trh;
      #pragma unroll
      for (int rg = 0; rg < 4; ++rg) {
        u64 kk[4];
        #pragma unroll
        for (int tc = 0; tc < 4; ++tc) {
          const int col = colbase + tc * 16;
          const float v = (col < V_ROWS) ? acc[tr][tc][rg] : -INFINITY;  // pad-col mask
          kk[tc] = pack_key(v, col);
        }
        const bool s01 = kk[0] > kk[1];
        u64 a0 = s01 ? kk[0] : kk[1], a1 = s01 ? kk[1] : kk[0];
        const bool s23 = kk[2] > kk[3];
        u64 b0 = s23 ? kk[2] : kk[3], b1 = s23 ? kk[3] : kk[2];
        kmerge(a0, a1, b0, b1);                       // sorted top-2 of 4 tc
        const int slot = wr * 32 + trh * 16 + lq * 4 + rg;
        ep[slot][(wc * 16 + lr) ^ (slot & 7)] = make_ulonglong2(a0, a1);
      }
    }
    __syncthreads();
    {
      // 4 threads per row merge 8 sorted pairs each, then quad-combine.
      const int ms = tid >> 2, q = tid & 3;
      u64 k0 = 0, k1 = 0;                             // 0 < any real key
      #pragma unroll
      for (int k = 0; k < 8; ++k) {
        ulonglong2 e = ep[ms][(q * 8 + k) ^ (ms & 7)];
        kmerge(k0, k1, e.x, e.y);
      }
      #pragma unroll
      for (int d = 1; d < 4; d <<= 1) {
        u64 o0 = __shfl_xor(k0, d), o1 = __shfl_xor(k1, d);
        kmerge(k0, k1, o0, o1);
      }
      if (q == 0) {
        const int row = (ms >> 5) * 64 + p * 32 + (ms & 31);
        // transposed layout: [row][tile] so finalize reads are coalesced
        cands[(size_t)(m0 + row) * NT_PAD + nt] = make_ulonglong2(k0, k1);
      }
    }
    __syncthreads();   // LDS reused by next pass
  }
}

// ---------------------------------------------------------------------------
// K5: per-row final. Merge 391 packed tile candidate pairs -> global top-2
// indices (u64 compares only; values never unpacked), then recompute
// d_pos / d_neg exactly in fp32 from the original inputs. Per-row contrib,
// no single-address atomics.
// ---------------------------------------------------------------------------
__global__ __launch_bounds__(256)
void finalize_kernel(const float* __restrict__ input, const float* __restrict__ target,
                     const float* __restrict__ veclist, const ulonglong2* __restrict__ cands,
                     float* __restrict__ contrib) {
  const int b = blockIdx.x;
  const int t = threadIdx.x;
  __shared__ ulonglong2 wpair[4];
  __shared__ int sidx[2];
  __shared__ float red[4][7];
  __shared__ int reda[4];

  // phase A: global top-2 across tiles (coalesced: cands[b][nt])
  u64 k0 = 0, k1 = 0;
  for (int nt = t; nt < NTILES; nt += 256) {
    ulonglong2 c = cands[(size_t)b * NT_PAD + nt];
    kmerge(k0, k1, c.x, c.y);
  }
  #pragma unroll
  for (int d = 1; d < 64; d <<= 1) {
    u64 o0 = __shfl_xor(k0, d), o1 = __shfl_xor(k1, d);
    kmerge(k0, k1, o0, o1);
  }
  if ((t & 63) == 0) wpair[t >> 6] = make_ulonglong2(k0, k1);
  __syncthreads();
  if (t == 0) {
    u64 m0k = wpair[0].x, m1k = wpair[0].y;
    for (int wd = 1; wd < 4; ++wd) kmerge(m0k, m1k, wpair[wd].x, wpair[wd].y);
    sidx[0] = key_col(m0k);
    sidx[1] = key_col(m1k);
  }
  __syncthreads();
  const int idx0 = sidx[0], idx1 = sidx[1];

  // phase B: exact fp32 dot products / norms
  const float2* xin = (const float2*)(input  + (size_t)b * DIMS);
  const float2* xtg = (const float2*)(target + (size_t)b * DIMS);
  const float2* xv0 = (const float2*)(veclist + (size_t)idx0 * DIMS);
  const float2* xv1 = (const float2*)(veclist + (size_t)idx1 * DIMS);
  float2 xi = xin[t], tg = xtg[t], a0 = xv0[t], a1 = xv1[t];
  float s[7];
  s[0] = xi.x * xi.x + xi.y * xi.y;
  s[1] = tg.x * tg.x + tg.y * tg.y;
  s[2] = xi.x * tg.x + xi.y * tg.y;
  s[3] = a0.x * a0.x + a0.y * a0.y;
  s[4] = xi.x * a0.x + xi.y * a0.y;
  s[5] = a1.x * a1.x + a1.y * a1.y;
  s[6] = xi.x * a1.x + xi.y * a1.y;
  bool eq = (a0.x == tg.x) && (a0.y == tg.y);
  int weq = __all(eq);
  #pragma unroll
  for (int k = 0; k < 7; ++k)
    #pragma unroll
    for (int d = 1; d < 64; d <<= 1) s[k] += __shfl_xor(s[k], d);
  if ((t & 63) == 0) {
    #pragma unroll
    for (int k = 0; k < 7; ++k) red[t >> 6][k] = s[k];
    reda[t >> 6] = weq;
  }
  __syncthreads();
  if (t == 0) {
    float r[7];
    #pragma unroll
    for (int k = 0; k < 7; ++k)
      r[k] = red[0][k] + red[1][k] + red[2][k] + red[3][k];
    bool eq0 = reda[0] && reda[1] && reda[2] && reda[3];
    float na  = fmaxf(sqrtf(r[0]), EPSF);
    float ntg = fmaxf(sqrtf(r[1]), EPSF);
    float simp = r[2] / (na * ntg);
    float d_pos = sqrtf(fmaxf(2.0f * (1.0f - simp), 1e-12f));
    float nn = eq0 ? fmaxf(sqrtf(r[5]), EPSF) : fmaxf(sqrtf(r[3]), EPSF);
    float dn = eq0 ? r[6] : r[4];
    float simn = dn / (na * nn);
    float d_neg = sqrtf(fmaxf(2.0f * (1.0f - simn), 1e-12f));
    float margin = 0.5f + d_pos - d_neg;          // GAMMA + d_pos - d_neg
    contrib[b] = 2.0f * fmaxf(margin, 0.0f) * (1.0f / (float)B_ROWS);  // RANK=2
  }
}

// ---------------------------------------------------------------------------
// K6: sum 4096 per-row contributions -> out[0]. One block, no atomics.
// ---------------------------------------------------------------------------
__global__ __launch_bounds__(256)
void reduce_kernel(const float* __restrict__ contrib, float* __restrict__ out) {
  const int t = threadIdx.x;
  __shared__ float wsum[4];
  float s = 0.0f;
  for (int i = t; i < B_ROWS; i += 256) s += contrib[i];
  #pragma unroll
  for (int d = 1; d < 64; d <<= 1) s += __shfl_xor(s, d);
  if ((t & 63) == 0) wsum[t >> 6] = s;
  __syncthreads();
  if (t == 0) out[0] = wsum[0] + wsum[1] + wsum[2] + wsum[3];
}

// ---------------------------------------------------------------------------
// Workspace layout (bytes):
//   vnn  fp8 [50048][512]          @ 0          : 25,624,576  (row-major)
//   apk  fp8 packed A-fragments    @ 25,624,576 :  2,097,152  (2048 x 1KB recs)
//   cands ulonglong2 [4096][392]   @ 27,721,728 : 25,690,112
//   contrib float [4096]           @ 53,411,840 :     16,384   (total ~53.4 MB)
// ---------------------------------------------------------------------------
extern "C" void kernel_launch(void* const* d_in, const int* in_sizes, int n_in,
                              void* d_out, int out_size, void* d_ws, size_t ws_size,
                              hipStream_t stream) {
  const float* input   = (const float*)d_in[0];
  const float* target  = (const float*)d_in[1];
  const float* veclist = (const float*)d_in[2];
  float* out = (float*)d_out;
  char* ws = (char*)d_ws;
  unsigned char* vnn = (unsigned char*)ws;
  unsigned char* apk = (unsigned char*)(ws + 25624576);
  ulonglong2* cands = (ulonglong2*)(ws + 27721728);
  float* contrib = (float*)(ws + 53411840);

  normalize_rows_kernel<<<4096, 256, 0, stream>>>(veclist, input, vnn, apk);
  gemm_top2_kernel<<<MTILES * NTILES, 256, 0, stream>>>(apk, vnn, cands);
  finalize_kernel<<<B_ROWS, 256, 0, stream>>>(input, target, veclist, cands, contrib);
  reduce_kernel<<<1, 256, 0, stream>>>(contrib, out);
}

// Round 5
// 353.556 us; speedup vs baseline: 1.6260x; 1.0253x over previous
//
#include <hip/hip_runtime.h>
#include <hip/hip_bf16.h>
#include <hip/hip_fp8.h>
#include <math.h>

// Problem constants (fixed by setup_inputs): B=4096, D=512, V=50000.
#define B_ROWS 4096
#define DIMS   512
#define V_ROWS 50000
#define V_PAD  50048            // 391 * 128
#define NTILES 391              // V_PAD / 128
#define NT_VIRT 392             // 8 XCDs x 49 nt-slots (1 dead)
#define NT_PAD 392              // cands row stride (ulonglong2 units)
#define MTILES 32               // B_ROWS / 128
#define NROWS_ALL 54144         // V_PAD + B_ROWS (fused normalize grid-stride range)
#define EPSF   1e-8f
#define QSCALE 64.0f            // row pre-scale before fp8 quant (dodges e4m3 subnormals)
#define SCALE1 0x7F7F7F7F       // E8M0 unity scale broadcast to all 4 bytes

typedef float f32x4 __attribute__((ext_vector_type(4)));
typedef int   i32x4 __attribute__((ext_vector_type(4)));
typedef int   i32x8 __attribute__((ext_vector_type(8)));
typedef unsigned long long u64;

// fp8 e4m3 (OCP) pack of 4 floats -> u32, bytes little-endian in k order
__device__ __forceinline__ unsigned int pk4_fp8(float a, float b, float c, float d) {
#if __has_builtin(__builtin_amdgcn_cvt_pk_fp8_f32)
  int w = __builtin_amdgcn_cvt_pk_fp8_f32(a, b, 0, false);   // bytes 0,1
  w = __builtin_amdgcn_cvt_pk_fp8_f32(c, d, w, true);        // bytes 2,3
  return (unsigned int)w;
#else
  __hip_fp8_e4m3 qa(a), qb(b), qc(c), qd(d);
  return (unsigned int)qa.__x | ((unsigned int)qb.__x << 8) |
         ((unsigned int)qc.__x << 16) | ((unsigned int)qd.__x << 24);
#endif
}

// async global->LDS, 16B per lane. LDS dest is wave-uniform base + lane*16.
__device__ __forceinline__ void lds_load16(const void* g, void* l) {
  __builtin_amdgcn_global_load_lds(
      (const __attribute__((address_space(1))) void*)g,
      (__attribute__((address_space(3))) void*)l, 16, 0, 0);
}

// ---------------------------------------------------------------------------
// Packed top-2 keys. key = (sortable(v) << 32) | ~col.
// u64 compare == (value desc, col asc) — matches jax top_k first-occurrence
// tie-break exactly. Keys within a row are always distinct (distinct cols).
// ---------------------------------------------------------------------------
__device__ __forceinline__ u64 pack_key(float v, int col) {
  unsigned int u = __float_as_uint(v);
  unsigned int s = u ^ ((unsigned int)((int)u >> 31) | 0x80000000u);
  return ((u64)s << 32) | (unsigned int)(~col);
}
__device__ __forceinline__ int key_col(u64 k) {
  return (int)(~(unsigned int)k);
}
// merge sorted pair (a0>=a1) into running sorted top-2 (k0>=k1)
__device__ __forceinline__ void kmerge(u64& k0, u64& k1, u64 a0, u64 a1) {
  bool bt = a0 > k0;
  u64 lo = bt ? k0 : a0;        // loser of the top comparison
  u64 hi = bt ? a1 : k1;        // runner-up of the winner's pair
  k0 = bt ? a0 : k0;
  k1 = hi > lo ? hi : lo;
}

// ---------------------------------------------------------------------------
// K1 (fused): row-normalize fp32 -> fp8 e4m3 (scaled by QSCALE).
//   veclist rows [0,V_PAD): row-major fp8 (pad rows zero-filled) — GEMM
//     B-operand, staged through LDS.
//   input rows [V_PAD,..): written in PACKED A-FRAGMENT layout (r10):
//     record(mt,wr,ks,tr,half) = 1KB = 64 lane-slots x 16B, where the GEMM
//     lane l=(lq*16+lr) of wave-row wr reads slot l of record (ks,tr,half)
//     as bytes k=[128ks+32lq+16half, +16) of A-row m0+wr*64+tr*16+lr.
//     Wave-contiguous 1KB dwordx4 A-loads (no LDS round-trip, no line
//     split). Same linear k-map as the B LDS path (XOR swizzle cancels),
//     so the A/B mapping-consistency invariant (absmax 0) is preserved.
//   Writer-side decode for row m, lane l holding bytes [8l, 8l+8):
//     ks=l>>4, lq=(l>>2)&3, half=(l>>1)&1, byte=(l&1)*8;
//     rec = ((((m>>7)*2 + ((m>>6)&1))*4 + ks)*4 + ((m>>4)&3))*2 + half
//     off = rec*1024 + (lq*16 + (m&15))*16 + (l&1)*8   (8B uint2 store)
// ---------------------------------------------------------------------------
__global__ __launch_bounds__(256)
void normalize_rows_kernel(const float* __restrict__ vsrc, const float* __restrict__ isrc,
                           unsigned char* __restrict__ vdst, unsigned char* __restrict__ apk) {
  const int l = threadIdx.x & 63;
  const int gw = (blockIdx.x * 256 + threadIdx.x) >> 6;
  const int nw = (gridDim.x * 256) >> 6;
  for (int row = gw; row < NROWS_ALL; row += nw) {
    const float* src;
    if (row < V_PAD) {
      if (row >= V_ROWS) {           // zero-fill pad rows
        *(uint2*)&vdst[(size_t)row * DIMS + l * 8] = make_uint2(0u, 0u);
        continue;
      }
      src = vsrc + (size_t)row * DIMS;
    } else {
      src = isrc + (size_t)(row - V_PAD) * DIMS;
    }
    float4 v0 = ((const float4*)src)[l * 2];
    float4 v1 = ((const float4*)src)[l * 2 + 1];
    float ss = v0.x * v0.x + v0.y * v0.y + v0.z * v0.z + v0.w * v0.w
             + v1.x * v1.x + v1.y * v1.y + v1.z * v1.z + v1.w * v1.w;
    #pragma unroll
    for (int d = 1; d < 64; d <<= 1) ss += __shfl_xor(ss, d);
    float s = QSCALE / fmaxf(sqrtf(ss), EPSF);
    uint2 o;
    o.x = pk4_fp8(v0.x * s, v0.y * s, v0.z * s, v0.w * s);
    o.y = pk4_fp8(v1.x * s, v1.y * s, v1.z * s, v1.w * s);
    if (row < V_PAD) {
      *(uint2*)&vdst[(size_t)row * DIMS + l * 8] = o;
    } else {
      const int m = row - V_PAD;
      const int rec = (((( (m >> 7) * 2 + ((m >> 6) & 1) ) * 4 + (l >> 4)) * 4
                        + ((m >> 4) & 3)) * 2 + ((l >> 1) & 1));
      const int off = rec * 1024 + (((l >> 2) & 3) * 16 + (m & 15)) * 16 + (l & 1) * 8;
      *(uint2*)&apk[off] = o;
    }
  }
}

// ---------------------------------------------------------------------------
// K3: MX-scaled fp8 MFMA GEMM (mfma_scale_f32_16x16x128_f8f6f4, unity E8M0).
// r11: XCD-PINNED block swizzle (T1). r10 counters: FETCH 108MB vs 27.6MB
// unique = 4x B-tile re-fetch; with nt=bid>>5 the 32 blocks sharing a B-tile
// round-robin across all 8 XCDs -> every XCD pulls the tile from L3/HBM and
// staging barriers eat L3-class latency (the 6900cy/ks mystery stall).
// New mapping (assumes XCD = bid % 8, m09 round-robin):
//   xcd = bid&7; g = bid>>3; ntl = g>>5; mt = g&31; nt = xcd*49 + ntl
// => all 32 blocks of an nt share bid%8 (one XCD, fetched once, 31 L2 hits)
//    and sit in a 256-bid dispatch window (temporal locality). Per-XCD B
//    working set = 49 x 64KB = 3.1MB <= 4MB L2 -> B fully L2-resident.
// nt==391 (32 blocks) is a dead pad tile: exit before any load (bounds).
// Compute core + epilogue byte-identical to the r10 absmax-0 version.
// ---------------------------------------------------------------------------
__global__ __launch_bounds__(256, 3)
void gemm_top2_kernel(const unsigned char* __restrict__ Apk,
                      const unsigned char* __restrict__ B8,
                      ulonglong2* __restrict__ cands) {
  __shared__ __align__(16) unsigned char Bs[128 * 128];   // 16 KB B stage
  __shared__ __align__(16) ulonglong2 ep[64][32];         // 32 KB epilogue

  const int bid = blockIdx.x;
  const int xcd = bid & 7;
  const int g   = bid >> 3;
  const int mt  = g & 31;
  const int nt  = xcd * 49 + (g >> 5);   // 0..391
  if (nt >= NTILES) return;              // dead pad tile (32 blocks)
  const int m0 = mt * 128, n0 = nt * 128;

  const int tid = threadIdx.x;
  const int w = tid >> 6, l = tid & 63;
  const int wr = w >> 1, wc = w & 1;     // 2x2 wave grid, 64x64 per wave
  const int lq = l >> 4, lr = l & 15;
  const int h = lr & 7;                  // XOR swizzle key (B path)

  // B fragment slot offsets (constant across k0) — byte-identical to r7
  const int s0 = ((2 * lq) ^ h) * 16;    // byte offset of chunk 2lq
  const int s1 = ((2 * lq + 1) ^ h) * 16;

  // packed-A base for this thread: record block (mt,wr), lane slot l
  const unsigned char* const Abase =
      Apk + (size_t)(mt * 2 + wr) * 32768 + l * 16;

  f32x4 acc[4][4] = {};

  for (int ks = 0; ks < 4; ++ks) {
    // stage B fp8 tile: 1024 16B-chunks (128 rows x 8 chunks), XOR-8 swizzle
    #pragma unroll
    for (int it = 0; it < 4; ++it) {
      const int chunk = it * 256 + w * 64 + l;   // 0..1023
      const int row = chunk >> 3, c = chunk & 7;
      const int gc = c ^ (row & 7);              // swizzled global chunk
      lds_load16(B8 + (size_t)(n0 + row) * DIMS + ks * 128 + gc * 16,
                 &Bs[(it * 256 + w * 64) * 16]);
    }
    // A fragments direct from packed global (8 x wave-contiguous dwordx4);
    // the __syncthreads drain below completes them exactly when needed.
    i32x4 areg[4][2];
    #pragma unroll
    for (int tr = 0; tr < 4; ++tr) {
      areg[tr][0] = *(const i32x4*)(Abase + ks * 8192 + tr * 2048);
      areg[tr][1] = *(const i32x4*)(Abase + ks * 8192 + tr * 2048 + 1024);
    }
    __syncthreads();

    // B fragments for all 4 col-tiles (32 VGPRs live) — byte-identical r7
    i32x8 bf[4];
    #pragma unroll
    for (int tc = 0; tc < 4; ++tc) {
      const int rb = (wc * 64 + tc * 16 + lr) * 128;
      i32x4 blo = *(const i32x4*)&Bs[rb + s0];
      i32x4 bhi = *(const i32x4*)&Bs[rb + s1];
      bf[tc] = __builtin_shufflevector(blo, bhi, 0, 1, 2, 3, 4, 5, 6, 7);
    }
    // A fragments one row-tile at a time; 4 MFMAs each
    #pragma unroll
    for (int tr = 0; tr < 4; ++tr) {
      i32x8 af = __builtin_shufflevector(areg[tr][0], areg[tr][1],
                                         0, 1, 2, 3, 4, 5, 6, 7);
      #pragma unroll
      for (int tc = 0; tc < 4; ++tc)
        acc[tr][tc] = __builtin_amdgcn_mfma_scale_f32_16x16x128_f8f6f4(
            af, bf[tc], acc[tr][tc],
            0, 0,                 // cbsz = fp8(e4m3), blgp = fp8(e4m3)
            0, SCALE1,            // scale_a opsel, scale_a (unity all bytes)
            0, SCALE1);           // scale_b opsel, scale_b
    }
    __syncthreads();
  }

  // ---- epilogue: per-row top-2 over this block's 128 cols (packed u64) ----
  // C/D layout: row = (lane>>4)*4 + reg, col = lane&15 (per 16x16 tile).
  // ep: 64 slots x 32 entries x 16 B = 32 KB (dedicated scratch).
  // slot = wr*32 + trh*16 + lq*4 + reg  ->  row = (slot>>5)*64 + p*32 + (slot&31)
  const int colbase = n0 + wc * 64 + lr;

  #pragma unroll
  for (int p = 0; p < 2; ++p) {
    #pragma unroll
    for (int trh = 0; trh < 2; ++trh) {
      const int tr = p * 2 + trh;
      #pragma unroll
      for (int rg = 0; rg < 4; ++rg) {
        u64 kk[4];
        #pragma unroll
        for (int tc = 0; tc < 4; ++tc) {
          const int col = colbase + tc * 16;
          const float v = (col < V_ROWS) ? acc[tr][tc][rg] : -INFINITY;  // pad-col mask
          kk[tc] = pack_key(v, col);
        }
        const bool s01 = kk[0] > kk[1];
        u64 a0 = s01 ? kk[0] : kk[1], a1 = s01 ? kk[1] : kk[0];
        const bool s23 = kk[2] > kk[3];
        u64 b0 = s23 ? kk[2] : kk[3], b1 = s23 ? kk[3] : kk[2];
        kmerge(a0, a1, b0, b1);                       // sorted top-2 of 4 tc
        const int slot = wr * 32 + trh * 16 + lq * 4 + rg;
        ep[slot][(wc * 16 + lr) ^ (slot & 7)] = make_ulonglong2(a0, a1);
      }
    }
    __syncthreads();
    {
      // 4 threads per row merge 8 sorted pairs each, then quad-combine.
      const int ms = tid >> 2, q = tid & 3;
      u64 k0 = 0, k1 = 0;                             // 0 < any real key
      #pragma unroll
      for (int k = 0; k < 8; ++k) {
        ulonglong2 e = ep[ms][(q * 8 + k) ^ (ms & 7)];
        kmerge(k0, k1, e.x, e.y);
      }
      #pragma unroll
      for (int d = 1; d < 4; d <<= 1) {
        u64 o0 = __shfl_xor(k0, d), o1 = __shfl_xor(k1, d);
        kmerge(k0, k1, o0, o1);
      }
      if (q == 0) {
        const int row = (ms >> 5) * 64 + p * 32 + (ms & 31);
        // transposed layout: [row][tile] so finalize reads are coalesced
        cands[(size_t)(m0 + row) * NT_PAD + nt] = make_ulonglong2(k0, k1);
      }
    }
    __syncthreads();   // LDS reused by next pass
  }
}

// ---------------------------------------------------------------------------
// K5: per-row final. Merge 391 packed tile candidate pairs -> global top-2
// indices (u64 compares only; values never unpacked), then recompute
// d_pos / d_neg exactly in fp32 from the original inputs. Per-row contrib,
// no single-address atomics.
// ---------------------------------------------------------------------------
__global__ __launch_bounds__(256)
void finalize_kernel(const float* __restrict__ input, const float* __restrict__ target,
                     const float* __restrict__ veclist, const ulonglong2* __restrict__ cands,
                     float* __restrict__ contrib) {
  const int b = blockIdx.x;
  const int t = threadIdx.x;
  __shared__ ulonglong2 wpair[4];
  __shared__ int sidx[2];
  __shared__ float red[4][7];
  __shared__ int reda[4];

  // phase A: global top-2 across tiles (coalesced: cands[b][nt])
  u64 k0 = 0, k1 = 0;
  for (int nt = t; nt < NTILES; nt += 256) {
    ulonglong2 c = cands[(size_t)b * NT_PAD + nt];
    kmerge(k0, k1, c.x, c.y);
  }
  #pragma unroll
  for (int d = 1; d < 64; d <<= 1) {
    u64 o0 = __shfl_xor(k0, d), o1 = __shfl_xor(k1, d);
    kmerge(k0, k1, o0, o1);
  }
  if ((t & 63) == 0) wpair[t >> 6] = make_ulonglong2(k0, k1);
  __syncthreads();
  if (t == 0) {
    u64 m0k = wpair[0].x, m1k = wpair[0].y;
    for (int wd = 1; wd < 4; ++wd) kmerge(m0k, m1k, wpair[wd].x, wpair[wd].y);
    sidx[0] = key_col(m0k);
    sidx[1] = key_col(m1k);
  }
  __syncthreads();
  const int idx0 = sidx[0], idx1 = sidx[1];

  // phase B: exact fp32 dot products / norms
  const float2* xin = (const float2*)(input  + (size_t)b * DIMS);
  const float2* xtg = (const float2*)(target + (size_t)b * DIMS);
  const float2* xv0 = (const float2*)(veclist + (size_t)idx0 * DIMS);
  const float2* xv1 = (const float2*)(veclist + (size_t)idx1 * DIMS);
  float2 xi = xin[t], tg = xtg[t], a0 = xv0[t], a1 = xv1[t];
  float s[7];
  s[0] = xi.x * xi.x + xi.y * xi.y;
  s[1] = tg.x * tg.x + tg.y * tg.y;
  s[2] = xi.x * tg.x + xi.y * tg.y;
  s[3] = a0.x * a0.x + a0.y * a0.y;
  s[4] = xi.x * a0.x + xi.y * a0.y;
  s[5] = a1.x * a1.x + a1.y * a1.y;
  s[6] = xi.x * a1.x + xi.y * a1.y;
  bool eq = (a0.x == tg.x) && (a0.y == tg.y);
  int weq = __all(eq);
  #pragma unroll
  for (int k = 0; k < 7; ++k)
    #pragma unroll
    for (int d = 1; d < 64; d <<= 1) s[k] += __shfl_xor(s[k], d);
  if ((t & 63) == 0) {
    #pragma unroll
    for (int k = 0; k < 7; ++k) red[t >> 6][k] = s[k];
    reda[t >> 6] = weq;
  }
  __syncthreads();
  if (t == 0) {
    float r[7];
    #pragma unroll
    for (int k = 0; k < 7; ++k)
      r[k] = red[0][k] + red[1][k] + red[2][k] + red[3][k];
    bool eq0 = reda[0] && reda[1] && reda[2] && reda[3];
    float na  = fmaxf(sqrtf(r[0]), EPSF);
    float ntg = fmaxf(sqrtf(r[1]), EPSF);
    float simp = r[2] / (na * ntg);
    float d_pos = sqrtf(fmaxf(2.0f * (1.0f - simp), 1e-12f));
    float nn = eq0 ? fmaxf(sqrtf(r[5]), EPSF) : fmaxf(sqrtf(r[3]), EPSF);
    float dn = eq0 ? r[6] : r[4];
    float simn = dn / (na * nn);
    float d_neg = sqrtf(fmaxf(2.0f * (1.0f - simn), 1e-12f));
    float margin = 0.5f + d_pos - d_neg;          // GAMMA + d_pos - d_neg
    contrib[b] = 2.0f * fmaxf(margin, 0.0f) * (1.0f / (float)B_ROWS);  // RANK=2
  }
}

// ---------------------------------------------------------------------------
// K6: sum 4096 per-row contributions -> out[0]. One block, no atomics.
// ---------------------------------------------------------------------------
__global__ __launch_bounds__(256)
void reduce_kernel(const float* __restrict__ contrib, float* __restrict__ out) {
  const int t = threadIdx.x;
  __shared__ float wsum[4];
  float s = 0.0f;
  for (int i = t; i < B_ROWS; i += 256) s += contrib[i];
  #pragma unroll
  for (int d = 1; d < 64; d <<= 1) s += __shfl_xor(s, d);
  if ((t & 63) == 0) wsum[t >> 6] = s;
  __syncthreads();
  if (t == 0) out[0] = wsum[0] + wsum[1] + wsum[2] + wsum[3];
}

// ---------------------------------------------------------------------------
// Workspace layout (bytes):
//   vnn  fp8 [50048][512]          @ 0          : 25,624,576  (row-major)
//   apk  fp8 packed A-fragments    @ 25,624,576 :  2,097,152  (2048 x 1KB recs)
//   cands ulonglong2 [4096][392]   @ 27,721,728 : 25,690,112
//   contrib float [4096]           @ 53,411,840 :     16,384   (total ~53.4 MB)
// ---------------------------------------------------------------------------
extern "C" void kernel_launch(void* const* d_in, const int* in_sizes, int n_in,
                              void* d_out, int out_size, void* d_ws, size_t ws_size,
                              hipStream_t stream) {
  const float* input   = (const float*)d_in[0];
  const float* target  = (const float*)d_in[1];
  const float* veclist = (const float*)d_in[2];
  float* out = (float*)d_out;
  char* ws = (char*)d_ws;
  unsigned char* vnn = (unsigned char*)ws;
  unsigned char* apk = (unsigned char*)(ws + 25624576);
  ulonglong2* cands = (ulonglong2*)(ws + 27721728);
  float* contrib = (float*)(ws + 53411840);

  normalize_rows_kernel<<<4096, 256, 0, stream>>>(veclist, input, vnn, apk);
  gemm_top2_kernel<<<NT_VIRT * MTILES, 256, 0, stream>>>(apk, vnn, cands);
  finalize_kernel<<<B_ROWS, 256, 0, stream>>>(input, target, veclist, cands, contrib);
  reduce_kernel<<<1, 256, 0, stream>>>(contrib, out);
}

// Round 6
// 343.311 us; speedup vs baseline: 1.6745x; 1.0298x over previous
//
#include <hip/hip_runtime.h>
#include <hip/hip_bf16.h>
#include <hip/hip_fp8.h>
#include <math.h>

// Problem constants (fixed by setup_inputs): B=4096, D=512, V=50000.
#define B_ROWS 4096
#define DIMS   512
#define V_ROWS 50000
#define V_PAD  50048            // 391 * 128
#define NTILES 391              // V_PAD / 128
#define NT_VIRT 392             // 8 XCDs x 49 nt-slots (1 dead)
#define NT_PAD 392              // cands row stride (ulonglong2 units)
#define MTILES 32               // B_ROWS / 128
#define NROWS_ALL 54144         // V_PAD + B_ROWS (fused normalize grid-stride range)
#define EPSF   1e-8f
#define QSCALE 64.0f            // row pre-scale before fp8 quant (dodges e4m3 subnormals)
#define SCALE1 0x7F7F7F7F       // E8M0 unity scale broadcast to all 4 bytes

typedef float f32x4 __attribute__((ext_vector_type(4)));
typedef int   i32x4 __attribute__((ext_vector_type(4)));
typedef int   i32x8 __attribute__((ext_vector_type(8)));
typedef unsigned long long u64;

// fp8 e4m3 (OCP) pack of 4 floats -> u32, bytes little-endian in k order
__device__ __forceinline__ unsigned int pk4_fp8(float a, float b, float c, float d) {
#if __has_builtin(__builtin_amdgcn_cvt_pk_fp8_f32)
  int w = __builtin_amdgcn_cvt_pk_fp8_f32(a, b, 0, false);   // bytes 0,1
  w = __builtin_amdgcn_cvt_pk_fp8_f32(c, d, w, true);        // bytes 2,3
  return (unsigned int)w;
#else
  __hip_fp8_e4m3 qa(a), qb(b), qc(c), qd(d);
  return (unsigned int)qa.__x | ((unsigned int)qb.__x << 8) |
         ((unsigned int)qc.__x << 16) | ((unsigned int)qd.__x << 24);
#endif
}

// async global->LDS, 16B per lane. LDS dest is wave-uniform base + lane*16.
__device__ __forceinline__ void lds_load16(const void* g, void* l) {
  __builtin_amdgcn_global_load_lds(
      (const __attribute__((address_space(1))) void*)g,
      (__attribute__((address_space(3))) void*)l, 16, 0, 0);
}

// ---------------------------------------------------------------------------
// Packed top-2 keys. key = (sortable(v) << 32) | ~col.
// u64 compare == (value desc, col asc) — matches jax top_k first-occurrence
// tie-break exactly. Keys within a row are always distinct (distinct cols).
// ---------------------------------------------------------------------------
__device__ __forceinline__ u64 pack_key(float v, int col) {
  unsigned int u = __float_as_uint(v);
  unsigned int s = u ^ ((unsigned int)((int)u >> 31) | 0x80000000u);
  return ((u64)s << 32) | (unsigned int)(~col);
}
__device__ __forceinline__ int key_col(u64 k) {
  return (int)(~(unsigned int)k);
}
// merge sorted pair (a0>=a1) into running sorted top-2 (k0>=k1)
__device__ __forceinline__ void kmerge(u64& k0, u64& k1, u64 a0, u64 a1) {
  bool bt = a0 > k0;
  u64 lo = bt ? k0 : a0;        // loser of the top comparison
  u64 hi = bt ? a1 : k1;        // runner-up of the winner's pair
  k0 = bt ? a0 : k0;
  k1 = hi > lo ? hi : lo;
}

// ---------------------------------------------------------------------------
// K1 (fused): row-normalize fp32 -> fp8 e4m3 (scaled by QSCALE).
//   veclist rows [0,V_PAD): row-major fp8 (pad rows zero-filled) — GEMM
//     B-operand, staged through LDS.
//   input rows [V_PAD,..): written in PACKED A-FRAGMENT layout (r10):
//     record(mt,wr,ks,tr,half) = 1KB = 64 lane-slots x 16B, where the GEMM
//     lane l=(lq*16+lr) of wave-row wr reads slot l of record (ks,tr,half)
//     as bytes k=[128ks+32lq+16half, +16) of A-row m0+wr*64+tr*16+lr.
//     Wave-contiguous 1KB dwordx4 A-loads (no LDS round-trip, no line
//     split). Same linear k-map as the B LDS path (XOR swizzle cancels),
//     so the A/B mapping-consistency invariant (absmax 0) is preserved.
//   Writer-side decode for row m, lane l holding bytes [8l, 8l+8):
//     ks=l>>4, lq=(l>>2)&3, half=(l>>1)&1, byte=(l&1)*8;
//     rec = ((((m>>7)*2 + ((m>>6)&1))*4 + ks)*4 + ((m>>4)&3))*2 + half
//     off = rec*1024 + (lq*16 + (m&15))*16 + (l&1)*8   (8B uint2 store)
// ---------------------------------------------------------------------------
__global__ __launch_bounds__(256)
void normalize_rows_kernel(const float* __restrict__ vsrc, const float* __restrict__ isrc,
                           unsigned char* __restrict__ vdst, unsigned char* __restrict__ apk) {
  const int l = threadIdx.x & 63;
  const int gw = (blockIdx.x * 256 + threadIdx.x) >> 6;
  const int nw = (gridDim.x * 256) >> 6;
  for (int row = gw; row < NROWS_ALL; row += nw) {
    const float* src;
    if (row < V_PAD) {
      if (row >= V_ROWS) {           // zero-fill pad rows
        *(uint2*)&vdst[(size_t)row * DIMS + l * 8] = make_uint2(0u, 0u);
        continue;
      }
      src = vsrc + (size_t)row * DIMS;
    } else {
      src = isrc + (size_t)(row - V_PAD) * DIMS;
    }
    float4 v0 = ((const float4*)src)[l * 2];
    float4 v1 = ((const float4*)src)[l * 2 + 1];
    float ss = v0.x * v0.x + v0.y * v0.y + v0.z * v0.z + v0.w * v0.w
             + v1.x * v1.x + v1.y * v1.y + v1.z * v1.z + v1.w * v1.w;
    #pragma unroll
    for (int d = 1; d < 64; d <<= 1) ss += __shfl_xor(ss, d);
    float s = QSCALE / fmaxf(sqrtf(ss), EPSF);
    uint2 o;
    o.x = pk4_fp8(v0.x * s, v0.y * s, v0.z * s, v0.w * s);
    o.y = pk4_fp8(v1.x * s, v1.y * s, v1.z * s, v1.w * s);
    if (row < V_PAD) {
      *(uint2*)&vdst[(size_t)row * DIMS + l * 8] = o;
    } else {
      const int m = row - V_PAD;
      const int rec = (((( (m >> 7) * 2 + ((m >> 6) & 1) ) * 4 + (l >> 4)) * 4
                        + ((m >> 4) & 3)) * 2 + ((l >> 1) & 1));
      const int off = rec * 1024 + (((l >> 2) & 3) * 16 + (m & 15)) * 16 + (l & 1) * 8;
      *(uint2*)&apk[off] = o;
    }
  }
}

// ---------------------------------------------------------------------------
// K3: MX-scaled fp8 MFMA GEMM (mfma_scale_f32_16x16x128_f8f6f4, unity E8M0).
// r12: COUNTED-VMCNT B-PIPELINE AT 3 BLOCKS/CU.
//   r8 pipeline failed only because dbuf-both-operands cost 64KB LDS ->
//   2 blk/CU. With A direct-from-packed-global (r10), B-only dbuf = 2x16KB
//   and the 32KB epilogue scratch OVERLAYS the two B buffers (epilogue is
//   strictly after the last compute) -> 32KB total, 3 blk/CU preserved.
//   Per ks (fully unrolled): issue 8 A dwordx4 (per-wave, no barrier req)
//   -> compiler fence -> issue next B-stage (4 gload_lds) -> s_waitcnt
//   vmcnt(4) (A + own prior stage done; next stage's 4 in flight) ->
//   s_barrier -> ds_read B frags + 16 MFMA -> s_barrier. vmcnt never 0
//   mid-loop (T3/T4); next-tile L2 latency hides under a full compute.
//   Raw s_barrier is safe: all ds_reads are same-wave-consumed by MFMAs
//   (compiler lgkm waits) and gload_lds writes are vmcnt-tracked.
// XCD-pinned mapping (r11): xcd=bid&7; g=bid>>3; mt=g&31; nt=xcd*49+(g>>5);
// 32 blocks of an nt share one XCD L2 (B working set 3.1MB <= 4MB).
// Epilogue byte-identical to the r7/r10/r11 absmax-0 version.
// ---------------------------------------------------------------------------
__global__ __launch_bounds__(256, 3)
void gemm_top2_kernel(const unsigned char* __restrict__ Apk,
                      const unsigned char* __restrict__ B8,
                      ulonglong2* __restrict__ cands) {
  __shared__ __align__(16) unsigned char smem[2 * 128 * 128];  // 32 KB: Bs0|Bs1 (+ep overlay)

  const int bid = blockIdx.x;
  const int xcd = bid & 7;
  const int g   = bid >> 3;
  const int mt  = g & 31;
  const int nt  = xcd * 49 + (g >> 5);   // 0..391
  if (nt >= NTILES) return;              // dead pad tile (32 blocks)
  const int m0 = mt * 128, n0 = nt * 128;

  const int tid = threadIdx.x;
  const int w = tid >> 6, l = tid & 63;
  const int wr = w >> 1, wc = w & 1;     // 2x2 wave grid, 64x64 per wave
  const int lq = l >> 4, lr = l & 15;
  const int h = lr & 7;                  // XOR swizzle key (B path)

  // B fragment slot offsets (constant across ks) — byte-identical to r7
  const int s0 = ((2 * lq) ^ h) * 16;    // byte offset of chunk 2lq
  const int s1 = ((2 * lq + 1) ^ h) * 16;

  // packed-A base for this thread: record block (mt,wr), lane slot l
  const unsigned char* const Abase =
      Apk + (size_t)(mt * 2 + wr) * 32768 + l * 16;

  f32x4 acc[4][4] = {};
  i32x4 areg[4][2];

  // stage one 128x128B B tile (XOR-8 swizzled) into buffer `buf`
#define STAGEB(buf, ks)                                                       \
  {                                                                           \
    unsigned char* Bsb = smem + (buf) * 16384;                                \
    _Pragma("unroll")                                                         \
    for (int it = 0; it < 4; ++it) {                                          \
      const int chunk = it * 256 + w * 64 + l;   /* 0..1023 */                \
      const int row = chunk >> 3, c = chunk & 7;                              \
      const int gc = c ^ (row & 7);              /* swizzled global chunk */  \
      lds_load16(B8 + (size_t)(n0 + row) * DIMS + (ks) * 128 + gc * 16,       \
                 &Bsb[(it * 256 + w * 64) * 16]);                             \
    }                                                                         \
  }

  // 8 wave-contiguous dwordx4 A-fragment loads for K-step ks
#define ALOAD(ks)                                                             \
  {                                                                           \
    _Pragma("unroll")                                                         \
    for (int tr = 0; tr < 4; ++tr) {                                          \
      areg[tr][0] = *(const i32x4*)(Abase + (ks) * 8192 + tr * 2048);         \
      areg[tr][1] = *(const i32x4*)(Abase + (ks) * 8192 + tr * 2048 + 1024);  \
    }                                                                         \
  }

  // one K=128 step: 8 B-frag ds_reads, then per tr 4 MFMAs from areg
#define COMPUTE(buf)                                                          \
  {                                                                           \
    unsigned char* Bsb = smem + (buf) * 16384;                                \
    i32x8 bf[4];                                                              \
    _Pragma("unroll")                                                         \
    for (int tc = 0; tc < 4; ++tc) {                                          \
      const int rb = (wc * 64 + tc * 16 + lr) * 128;                          \
      i32x4 blo = *(const i32x4*)&Bsb[rb + s0];                               \
      i32x4 bhi = *(const i32x4*)&Bsb[rb + s1];                               \
      bf[tc] = __builtin_shufflevector(blo, bhi, 0, 1, 2, 3, 4, 5, 6, 7);     \
    }                                                                         \
    _Pragma("unroll")                                                         \
    for (int tr = 0; tr < 4; ++tr) {                                          \
      i32x8 af = __builtin_shufflevector(areg[tr][0], areg[tr][1],            \
                                         0, 1, 2, 3, 4, 5, 6, 7);             \
      _Pragma("unroll")                                                       \
      for (int tc = 0; tc < 4; ++tc)                                          \
        acc[tr][tc] = __builtin_amdgcn_mfma_scale_f32_16x16x128_f8f6f4(       \
            af, bf[tc], acc[tr][tc], 0, 0, 0, SCALE1, 0, SCALE1);             \
    }                                                                         \
  }

#define FENCE asm volatile("" ::: "memory")

  STAGEB(0, 0);
  // ks = 0
  ALOAD(0); FENCE;
  STAGEB(1, 1);
  asm volatile("s_waitcnt vmcnt(4)" ::: "memory");
  __builtin_amdgcn_s_barrier();
  COMPUTE(0);
  __builtin_amdgcn_s_barrier();
  // ks = 1
  ALOAD(1); FENCE;
  STAGEB(0, 2);
  asm volatile("s_waitcnt vmcnt(4)" ::: "memory");
  __builtin_amdgcn_s_barrier();
  COMPUTE(1);
  __builtin_amdgcn_s_barrier();
  // ks = 2
  ALOAD(2); FENCE;
  STAGEB(1, 3);
  asm volatile("s_waitcnt vmcnt(4)" ::: "memory");
  __builtin_amdgcn_s_barrier();
  COMPUTE(0);
  __builtin_amdgcn_s_barrier();
  // ks = 3 (no further stage; allow A3 to pend past the barrier — the
  // compiler inserts the exact vmcnt before the first areg use)
  ALOAD(3); FENCE;
  asm volatile("s_waitcnt vmcnt(8)" ::: "memory");
  __builtin_amdgcn_s_barrier();
  COMPUTE(1);
  __syncthreads();                       // drain before ep overlays Bs0|Bs1
#undef STAGEB
#undef ALOAD
#undef COMPUTE
#undef FENCE

  // ---- epilogue: per-row top-2 over this block's 128 cols (packed u64) ----
  // C/D layout: row = (lane>>4)*4 + reg, col = lane&15 (per 16x16 tile).
  // ep overlays Bs0|Bs1: 64 slots x 32 entries x 16 B = 32 KB exactly.
  // slot = wr*32 + trh*16 + lq*4 + reg  ->  row = (slot>>5)*64 + p*32 + (slot&31)
  ulonglong2 (*ep)[32] = (ulonglong2(*)[32])smem;
  const int colbase = n0 + wc * 64 + lr;

  #pragma unroll
  for (int p = 0; p < 2; ++p) {
    #pragma unroll
    for (int trh = 0; trh < 2; ++trh) {
      const int tr = p * 2 + trh;
      #pragma unroll
      for (int rg = 0; rg < 4; ++rg) {
        u64 kk[4];
        #pragma unroll
        for (int tc = 0; tc < 4; ++tc) {
          const int col = colbase + tc * 16;
          const float v = (col < V_ROWS) ? acc[tr][tc][rg] : -INFINITY;  // pad-col mask
          kk[tc] = pack_key(v, col);
        }
        const bool s01 = kk[0] > kk[1];
        u64 a0 = s01 ? kk[0] : kk[1], a1 = s01 ? kk[1] : kk[0];
        const bool s23 = kk[2] > kk[3];
        u64 b0 = s23 ? kk[2] : kk[3], b1 = s23 ? kk[3] : kk[2];
        kmerge(a0, a1, b0, b1);                       // sorted top-2 of 4 tc
        const int slot = wr * 32 + trh * 16 + lq * 4 + rg;
        ep[slot][(wc * 16 + lr) ^ (slot & 7)] = make_ulonglong2(a0, a1);
      }
    }
    __syncthreads();
    {
      // 4 threads per row merge 8 sorted pairs each, then quad-combine.
      const int ms = tid >> 2, q = tid & 3;
      u64 k0 = 0, k1 = 0;                             // 0 < any real key
      #pragma unroll
      for (int k = 0; k < 8; ++k) {
        ulonglong2 e = ep[ms][(q * 8 + k) ^ (ms & 7)];
        kmerge(k0, k1, e.x, e.y);
      }
      #pragma unroll
      for (int d = 1; d < 4; d <<= 1) {
        u64 o0 = __shfl_xor(k0, d), o1 = __shfl_xor(k1, d);
        kmerge(k0, k1, o0, o1);
      }
      if (q == 0) {
        const int row = (ms >> 5) * 64 + p * 32 + (ms & 31);
        // transposed layout: [row][tile] so finalize reads are coalesced
        cands[(size_t)(m0 + row) * NT_PAD + nt] = make_ulonglong2(k0, k1);
      }
    }
    __syncthreads();   // LDS reused by next pass
  }
}

// ---------------------------------------------------------------------------
// K5: per-row final. Merge 391 packed tile candidate pairs -> global top-2
// indices (u64 compares only; values never unpacked), then recompute
// d_pos / d_neg exactly in fp32 from the original inputs. Per-row contrib,
// no single-address atomics.
// ---------------------------------------------------------------------------
__global__ __launch_bounds__(256)
void finalize_kernel(const float* __restrict__ input, const float* __restrict__ target,
                     const float* __restrict__ veclist, const ulonglong2* __restrict__ cands,
                     float* __restrict__ contrib) {
  const int b = blockIdx.x;
  const int t = threadIdx.x;
  __shared__ ulonglong2 wpair[4];
  __shared__ int sidx[2];
  __shared__ float red[4][7];
  __shared__ int reda[4];

  // phase A: global top-2 across tiles (coalesced: cands[b][nt])
  u64 k0 = 0, k1 = 0;
  for (int nt = t; nt < NTILES; nt += 256) {
    ulonglong2 c = cands[(size_t)b * NT_PAD + nt];
    kmerge(k0, k1, c.x, c.y);
  }
  #pragma unroll
  for (int d = 1; d < 64; d <<= 1) {
    u64 o0 = __shfl_xor(k0, d), o1 = __shfl_xor(k1, d);
    kmerge(k0, k1, o0, o1);
  }
  if ((t & 63) == 0) wpair[t >> 6] = make_ulonglong2(k0, k1);
  __syncthreads();
  if (t == 0) {
    u64 m0k = wpair[0].x, m1k = wpair[0].y;
    for (int wd = 1; wd < 4; ++wd) kmerge(m0k, m1k, wpair[wd].x, wpair[wd].y);
    sidx[0] = key_col(m0k);
    sidx[1] = key_col(m1k);
  }
  __syncthreads();
  const int idx0 = sidx[0], idx1 = sidx[1];

  // phase B: exact fp32 dot products / norms
  const float2* xin = (const float2*)(input  + (size_t)b * DIMS);
  const float2* xtg = (const float2*)(target + (size_t)b * DIMS);
  const float2* xv0 = (const float2*)(veclist + (size_t)idx0 * DIMS);
  const float2* xv1 = (const float2*)(veclist + (size_t)idx1 * DIMS);
  float2 xi = xin[t], tg = xtg[t], a0 = xv0[t], a1 = xv1[t];
  float s[7];
  s[0] = xi.x * xi.x + xi.y * xi.y;
  s[1] = tg.x * tg.x + tg.y * tg.y;
  s[2] = xi.x * tg.x + xi.y * tg.y;
  s[3] = a0.x * a0.x + a0.y * a0.y;
  s[4] = xi.x * a0.x + xi.y * a0.y;
  s[5] = a1.x * a1.x + a1.y * a1.y;
  s[6] = xi.x * a1.x + xi.y * a1.y;
  bool eq = (a0.x == tg.x) && (a0.y == tg.y);
  int weq = __all(eq);
  #pragma unroll
  for (int k = 0; k < 7; ++k)
    #pragma unroll
    for (int d = 1; d < 64; d <<= 1) s[k] += __shfl_xor(s[k], d);
  if ((t & 63) == 0) {
    #pragma unroll
    for (int k = 0; k < 7; ++k) red[t >> 6][k] = s[k];
    reda[t >> 6] = weq;
  }
  __syncthreads();
  if (t == 0) {
    float r[7];
    #pragma unroll
    for (int k = 0; k < 7; ++k)
      r[k] = red[0][k] + red[1][k] + red[2][k] + red[3][k];
    bool eq0 = reda[0] && reda[1] && reda[2] && reda[3];
    float na  = fmaxf(sqrtf(r[0]), EPSF);
    float ntg = fmaxf(sqrtf(r[1]), EPSF);
    float simp = r[2] / (na * ntg);
    float d_pos = sqrtf(fmaxf(2.0f * (1.0f - simp), 1e-12f));
    float nn = eq0 ? fmaxf(sqrtf(r[5]), EPSF) : fmaxf(sqrtf(r[3]), EPSF);
    float dn = eq0 ? r[6] : r[4];
    float simn = dn / (na * nn);
    float d_neg = sqrtf(fmaxf(2.0f * (1.0f - simn), 1e-12f));
    float margin = 0.5f + d_pos - d_neg;          // GAMMA + d_pos - d_neg
    contrib[b] = 2.0f * fmaxf(margin, 0.0f) * (1.0f / (float)B_ROWS);  // RANK=2
  }
}

// ---------------------------------------------------------------------------
// K6: sum 4096 per-row contributions -> out[0]. One block, no atomics.
// ---------------------------------------------------------------------------
__global__ __launch_bounds__(256)
void reduce_kernel(const float* __restrict__ contrib, float* __restrict__ out) {
  const int t = threadIdx.x;
  __shared__ float wsum[4];
  float s = 0.0f;
  for (int i = t; i < B_ROWS; i += 256) s += contrib[i];
  #pragma unroll
  for (int d = 1; d < 64; d <<= 1) s += __shfl_xor(s, d);
  if ((t & 63) == 0) wsum[t >> 6] = s;
  __syncthreads();
  if (t == 0) out[0] = wsum[0] + wsum[1] + wsum[2] + wsum[3];
}

// ---------------------------------------------------------------------------
// Workspace layout (bytes):
//   vnn  fp8 [50048][512]          @ 0          : 25,624,576  (row-major)
//   apk  fp8 packed A-fragments    @ 25,624,576 :  2,097,152  (2048 x 1KB recs)
//   cands ulonglong2 [4096][392]   @ 27,721,728 : 25,690,112
//   contrib float [4096]           @ 53,411,840 :     16,384   (total ~53.4 MB)
// ---------------------------------------------------------------------------
extern "C" void kernel_launch(void* const* d_in, const int* in_sizes, int n_in,
                              void* d_out, int out_size, void* d_ws, size_t ws_size,
                              hipStream_t stream) {
  const float* input   = (const float*)d_in[0];
  const float* target  = (const float*)d_in[1];
  const float* veclist = (const float*)d_in[2];
  float* out = (float*)d_out;
  char* ws = (char*)d_ws;
  unsigned char* vnn = (unsigned char*)ws;
  unsigned char* apk = (unsigned char*)(ws + 25624576);
  ulonglong2* cands = (ulonglong2*)(ws + 27721728);
  float* contrib = (float*)(ws + 53411840);

  normalize_rows_kernel<<<4096, 256, 0, stream>>>(veclist, input, vnn, apk);
  gemm_top2_kernel<<<NT_VIRT * MTILES, 256, 0, stream>>>(apk, vnn, cands);
  finalize_kernel<<<B_ROWS, 256, 0, stream>>>(input, target, veclist, cands, contrib);
  reduce_kernel<<<1, 256, 0, stream>>>(contrib, out);
}

// Round 8
// 340.312 us; speedup vs baseline: 1.6892x; 1.0088x over previous
//
#include <hip/hip_runtime.h>
#include <hip/hip_bf16.h>
#include <hip/hip_fp8.h>
#include <math.h>

// Problem constants (fixed by setup_inputs): B=4096, D=512, V=50000.
#define B_ROWS 4096
#define DIMS   512
#define V_ROWS 50000
#define V_PAD  50048            // 391 * 128
#define NTILES 391              // V_PAD / 128
#define NT_VIRT 392             // 8 XCDs x 49 nt-slots (1 dead)
#define MTILES 32               // B_ROWS / 128
#define NROWS_ALL 54144         // V_PAD + B_ROWS (fused normalize grid-stride range)
#define EPSF   1e-8f
#define QSCALE 64.0f            // row pre-scale before fp8 quant (dodges e4m3 subnormals)
#define SCALE1 0x7F7F7F7F       // E8M0 unity scale broadcast to all 4 bytes

typedef float f32x4 __attribute__((ext_vector_type(4)));
typedef int   i32x4 __attribute__((ext_vector_type(4)));
typedef int   i32x8 __attribute__((ext_vector_type(8)));
typedef unsigned long long u64;

// fp8 e4m3 (OCP) pack of 4 floats -> u32, bytes little-endian in k order
__device__ __forceinline__ unsigned int pk4_fp8(float a, float b, float c, float d) {
#if __has_builtin(__builtin_amdgcn_cvt_pk_fp8_f32)
  int w = __builtin_amdgcn_cvt_pk_fp8_f32(a, b, 0, false);   // bytes 0,1
  w = __builtin_amdgcn_cvt_pk_fp8_f32(c, d, w, true);        // bytes 2,3
  return (unsigned int)w;
#else
  __hip_fp8_e4m3 qa(a), qb(b), qc(c), qd(d);
  return (unsigned int)qa.__x | ((unsigned int)qb.__x << 8) |
         ((unsigned int)qc.__x << 16) | ((unsigned int)qd.__x << 24);
#endif
}

// async global->LDS, 16B per lane. LDS dest is wave-uniform base + lane*16.
// r14 LESSON: the builtin's `offset` arg must be a plain literal (r13 passed
// a template-dependent constant -> silently wrong staging -> absmax 0.273).
// Express any constant offset in the POINTER; the compiler folds it into the
// instruction's 13-bit imm on its own correct path.
__device__ __forceinline__ void lds_load16(const void* g, void* l) {
  __builtin_amdgcn_global_load_lds(
      (const __attribute__((address_space(1))) void*)g,
      (__attribute__((address_space(3))) void*)l, 16, 0, 0);
}

// ---------------------------------------------------------------------------
// Packed top-2 keys. key = (sortable(v) << 32) | ~col.
// u64 compare == (value desc, col asc) — matches jax top_k first-occurrence
// tie-break exactly. Keys within a row are always distinct (distinct cols).
// ~col precomputed per tc (reused 16x) — pack is 3 VALU + reg-pair.
// ---------------------------------------------------------------------------
__device__ __forceinline__ u64 pack_key2(float v, unsigned int ncol) {
  unsigned int u = __float_as_uint(v);
  unsigned int s = u ^ ((unsigned int)((int)u >> 31) | 0x80000000u);
  return ((u64)s << 32) | ncol;
}
__device__ __forceinline__ int key_col(u64 k) {
  return (int)(~(unsigned int)k);
}
// merge sorted pair (a0>=a1) into running sorted top-2 (k0>=k1)
__device__ __forceinline__ void kmerge(u64& k0, u64& k1, u64 a0, u64 a1) {
  bool bt = a0 > k0;
  u64 lo = bt ? k0 : a0;        // loser of the top comparison
  u64 hi = bt ? a1 : k1;        // runner-up of the winner's pair
  k0 = bt ? a0 : k0;
  k1 = hi > lo ? hi : lo;
}

// ---------------------------------------------------------------------------
// K1 (fused): row-normalize fp32 -> fp8 e4m3 (scaled by QSCALE).
//   veclist rows [0,V_PAD): row-major fp8 (pad rows zero-filled) — GEMM
//     B-operand, staged through LDS.
//   input rows [V_PAD,..): PACKED A-FRAGMENT layout (r10): record
//     (mt,wr,ks,tr,half) = 1KB = 64 lane-slots x 16B; GEMM lane l reads
//     slot l as bytes k=[128ks+32lq+16half,+16) of A-row m0+wr*64+tr*16+lr.
//     Wave-contiguous 1KB dwordx4 A-loads; same linear k-map as the B LDS
//     path (XOR swizzle cancels) -> A/B mapping-consistency (absmax 0).
//   Writer-side decode for row m, lane l holding bytes [8l, 8l+8):
//     rec = ((((m>>7)*2 + ((m>>6)&1))*4 + (l>>4))*4 + ((m>>4)&3))*2 + ((l>>1)&1)
//     off = rec*1024 + (((l>>2)&3)*16 + (m&15))*16 + (l&1)*8
// ---------------------------------------------------------------------------
__global__ __launch_bounds__(256)
void normalize_rows_kernel(const float* __restrict__ vsrc, const float* __restrict__ isrc,
                           unsigned char* __restrict__ vdst, unsigned char* __restrict__ apk) {
  const int l = threadIdx.x & 63;
  const int gw = (blockIdx.x * 256 + threadIdx.x) >> 6;
  const int nw = (gridDim.x * 256) >> 6;
  for (int row = gw; row < NROWS_ALL; row += nw) {
    const float* src;
    if (row < V_PAD) {
      if (row >= V_ROWS) {           // zero-fill pad rows
        *(uint2*)&vdst[(size_t)row * DIMS + l * 8] = make_uint2(0u, 0u);
        continue;
      }
      src = vsrc + (size_t)row * DIMS;
    } else {
      src = isrc + (size_t)(row - V_PAD) * DIMS;
    }
    float4 v0 = ((const float4*)src)[l * 2];
    float4 v1 = ((const float4*)src)[l * 2 + 1];
    float ss = v0.x * v0.x + v0.y * v0.y + v0.z * v0.z + v0.w * v0.w
             + v1.x * v1.x + v1.y * v1.y + v1.z * v1.z + v1.w * v1.w;
    #pragma unroll
    for (int d = 1; d < 64; d <<= 1) ss += __shfl_xor(ss, d);
    float s = QSCALE / fmaxf(sqrtf(ss), EPSF);
    uint2 o;
    o.x = pk4_fp8(v0.x * s, v0.y * s, v0.z * s, v0.w * s);
    o.y = pk4_fp8(v1.x * s, v1.y * s, v1.z * s, v1.w * s);
    if (row < V_PAD) {
      *(uint2*)&vdst[(size_t)row * DIMS + l * 8] = o;
    } else {
      const int m = row - V_PAD;
      const int rec = (((( (m >> 7) * 2 + ((m >> 6) & 1) ) * 4 + (l >> 4)) * 4
                        + ((m >> 4) & 3)) * 2 + ((l >> 1) & 1));
      const int off = rec * 1024 + (((l >> 2) & 3) * 16 + (m & 15)) * 16 + (l & 1) * 8;
      *(uint2*)&apk[off] = o;
    }
  }
}

// ---------------------------------------------------------------------------
// K3: MX-scaled fp8 MFMA GEMM (mfma_scale_f32_16x16x128_f8f6f4, unity E8M0).
// r14 = r13 with the staging offset moved back into the POINTER (the r13
// template-offset builtin arg was the absmax-0.273 bug; see lds_load16 note).
// Retained r13 VALU fixes:
//   - hoisted B staging bases (4 per-thread pointers computed once; per-ks
//     constant adds fold into the instruction imm offset)
//   - A-loads via 2 rolling pointers (+8192/ks), imm offsets <= 3072
//   - pad-col mask under block-uniform nt==390 branch; ~col per tc hoisted
//   - cands stored TRANSPOSED [nt][m]: contiguous 1KB runs, full-line writes
// Schedule (r12, verified): counted-vmcnt B-dbuf at 3 blk/CU, 32KB LDS,
// epilogue overlays Bs0|Bs1, vmcnt never 0 mid-loop.
// XCD-pinned mapping (r11): all 32 blocks of an nt share one XCD L2.
// ---------------------------------------------------------------------------
__global__ __launch_bounds__(256, 3)
void gemm_top2_kernel(const unsigned char* __restrict__ Apk,
                      const unsigned char* __restrict__ B8,
                      ulonglong2* __restrict__ cands) {
  __shared__ __align__(16) unsigned char smem[2 * 128 * 128];  // 32 KB: Bs0|Bs1 (+ep overlay)

  const int bid = blockIdx.x;
  const int xcd = bid & 7;
  const int g   = bid >> 3;
  const int mt  = g & 31;
  const int nt  = xcd * 49 + (g >> 5);   // 0..391
  if (nt >= NTILES) return;              // dead pad tile (32 blocks)
  const int m0 = mt * 128, n0 = nt * 128;

  const int tid = threadIdx.x;
  const int w = tid >> 6, l = tid & 63;
  const int wr = w >> 1, wc = w & 1;     // 2x2 wave grid, 64x64 per wave
  const int lq = l >> 4, lr = l & 15;
  const int h = lr & 7;                  // XOR swizzle key (B path)

  // B fragment slot offsets (constant across ks) — byte-identical to r7
  const int s0 = ((2 * lq) ^ h) * 16;    // byte offset of chunk 2lq
  const int s1 = ((2 * lq + 1) ^ h) * 16;

  // hoisted B staging bases: 4 per-thread global pointers
  const unsigned char* gB[4];
  unsigned char* ldsd[4];
  #pragma unroll
  for (int it = 0; it < 4; ++it) {
    const int chunk = it * 256 + w * 64 + l;   // 0..1023
    const int row = chunk >> 3, c = chunk & 7;
    const int gc = c ^ (row & 7);              // swizzled global chunk
    gB[it] = B8 + (size_t)(n0 + row) * DIMS + gc * 16;
    ldsd[it] = smem + (it * 256 + w * 64) * 16;
  }

  // rolling packed-A pointers: record block (mt,wr), lane slot l
  const unsigned char* aP0 = Apk + (size_t)(mt * 2 + wr) * 32768 + l * 16;
  const unsigned char* aP1 = aP0 + 4096;

  f32x4 acc[4][4] = {};
  i32x4 areg[4][2];

  // stage one 128x128B B tile into buffer `buf` at K-step ks; the constant
  // (ks)*128 lives in the pointer so the compiler folds it to the imm field
#define STAGEB(buf, ks)                                                       \
  {                                                                           \
    lds_load16(gB[0] + (ks) * 128, ldsd[0] + (buf) * 16384);                  \
    lds_load16(gB[1] + (ks) * 128, ldsd[1] + (buf) * 16384);                  \
    lds_load16(gB[2] + (ks) * 128, ldsd[2] + (buf) * 16384);                  \
    lds_load16(gB[3] + (ks) * 128, ldsd[3] + (buf) * 16384);                  \
  }

  // 8 wave-contiguous dwordx4 A-fragment loads; pointers advance 8192/ks
#define ALOAD()                                                               \
  {                                                                           \
    areg[0][0] = *(const i32x4*)(aP0);                                        \
    areg[0][1] = *(const i32x4*)(aP0 + 1024);                                 \
    areg[1][0] = *(const i32x4*)(aP0 + 2048);                                 \
    areg[1][1] = *(const i32x4*)(aP0 + 3072);                                 \
    areg[2][0] = *(const i32x4*)(aP1);                                        \
    areg[2][1] = *(const i32x4*)(aP1 + 1024);                                 \
    areg[3][0] = *(const i32x4*)(aP1 + 2048);                                 \
    areg[3][1] = *(const i32x4*)(aP1 + 3072);                                 \
    aP0 += 8192; aP1 += 8192;                                                 \
  }

  // one K=128 step: 8 B-frag ds_reads, then per tr 4 MFMAs from areg
#define COMPUTE(buf)                                                          \
  {                                                                           \
    unsigned char* Bsb = smem + (buf) * 16384;                                \
    i32x8 bf[4];                                                              \
    _Pragma("unroll")                                                         \
    for (int tc = 0; tc < 4; ++tc) {                                          \
      const int rb = (wc * 64 + tc * 16 + lr) * 128;                          \
      i32x4 blo = *(const i32x4*)&Bsb[rb + s0];                               \
      i32x4 bhi = *(const i32x4*)&Bsb[rb + s1];                               \
      bf[tc] = __builtin_shufflevector(blo, bhi, 0, 1, 2, 3, 4, 5, 6, 7);     \
    }                                                                         \
    _Pragma("unroll")                                                         \
    for (int tr = 0; tr < 4; ++tr) {                                          \
      i32x8 af = __builtin_shufflevector(areg[tr][0], areg[tr][1],            \
                                         0, 1, 2, 3, 4, 5, 6, 7);             \
      _Pragma("unroll")                                                       \
      for (int tc = 0; tc < 4; ++tc)                                          \
        acc[tr][tc] = __builtin_amdgcn_mfma_scale_f32_16x16x128_f8f6f4(       \
            af, bf[tc], acc[tr][tc], 0, 0, 0, SCALE1, 0, SCALE1);             \
    }                                                                         \
  }

#define FENCE asm volatile("" ::: "memory")

  STAGEB(0, 0);
  // ks = 0
  ALOAD(); FENCE;
  STAGEB(1, 1);
  asm volatile("s_waitcnt vmcnt(4)" ::: "memory");
  __builtin_amdgcn_s_barrier();
  COMPUTE(0);
  __builtin_amdgcn_s_barrier();
  // ks = 1
  ALOAD(); FENCE;
  STAGEB(0, 2);
  asm volatile("s_waitcnt vmcnt(4)" ::: "memory");
  __builtin_amdgcn_s_barrier();
  COMPUTE(1);
  __builtin_amdgcn_s_barrier();
  // ks = 2
  ALOAD(); FENCE;
  STAGEB(1, 3);
  asm volatile("s_waitcnt vmcnt(4)" ::: "memory");
  __builtin_amdgcn_s_barrier();
  COMPUTE(0);
  __builtin_amdgcn_s_barrier();
  // ks = 3 (no further stage; A3 may pend past the barrier — compiler
  // inserts the exact vmcnt before the first areg use)
  ALOAD(); FENCE;
  asm volatile("s_waitcnt vmcnt(8)" ::: "memory");
  __builtin_amdgcn_s_barrier();
  COMPUTE(1);
  __syncthreads();                       // drain before ep overlays Bs0|Bs1
#undef STAGEB
#undef ALOAD
#undef COMPUTE
#undef FENCE

  // ---- epilogue: per-row top-2 over this block's 128 cols (packed u64) ----
  // C/D layout: row = (lane>>4)*4 + reg, col = lane&15 (per 16x16 tile).
  // ep overlays Bs0|Bs1: 64 slots x 32 entries x 16 B = 32 KB exactly.
  // slot = wr*32 + trh*16 + lq*4 + reg  ->  row = (slot>>5)*64 + p*32 + (slot&31)
  ulonglong2 (*ep)[32] = (ulonglong2(*)[32])smem;
  const int colbase = n0 + wc * 64 + lr;

  // pad-col mask: only nt==390 has cols >= V_ROWS (block-uniform branch)
  if (n0 + 128 > V_ROWS) {
    #pragma unroll
    for (int tc = 0; tc < 4; ++tc) {
      if (colbase + tc * 16 >= V_ROWS) {
        #pragma unroll
        for (int tr = 0; tr < 4; ++tr)
          #pragma unroll
          for (int rg = 0; rg < 4; ++rg) acc[tr][tc][rg] = -INFINITY;
      }
    }
  }
  // ~col per tc, reused by all 16 (tr,rg) groups
  unsigned int nc[4];
  #pragma unroll
  for (int tc = 0; tc < 4; ++tc) nc[tc] = ~(unsigned int)(colbase + tc * 16);

  #pragma unroll
  for (int p = 0; p < 2; ++p) {
    #pragma unroll
    for (int trh = 0; trh < 2; ++trh) {
      const int tr = p * 2 + trh;
      #pragma unroll
      for (int rg = 0; rg < 4; ++rg) {
        u64 kk[4];
        #pragma unroll
        for (int tc = 0; tc < 4; ++tc)
          kk[tc] = pack_key2(acc[tr][tc][rg], nc[tc]);
        const bool s01 = kk[0] > kk[1];
        u64 a0 = s01 ? kk[0] : kk[1], a1 = s01 ? kk[1] : kk[0];
        const bool s23 = kk[2] > kk[3];
        u64 b0 = s23 ? kk[2] : kk[3], b1 = s23 ? kk[3] : kk[2];
        kmerge(a0, a1, b0, b1);                       // sorted top-2 of 4 tc
        const int slot = wr * 32 + trh * 16 + lq * 4 + rg;
        ep[slot][(wc * 16 + lr) ^ (slot & 7)] = make_ulonglong2(a0, a1);
      }
    }
    __syncthreads();
    {
      // 4 threads per row merge 8 sorted pairs each, then quad-combine.
      const int ms = tid >> 2, q = tid & 3;
      u64 k0 = 0, k1 = 0;                             // 0 < any real key
      #pragma unroll
      for (int k = 0; k < 8; ++k) {
        ulonglong2 e = ep[ms][(q * 8 + k) ^ (ms & 7)];
        kmerge(k0, k1, e.x, e.y);
      }
      #pragma unroll
      for (int d = 1; d < 4; d <<= 1) {
        u64 o0 = __shfl_xor(k0, d), o1 = __shfl_xor(k1, d);
        kmerge(k0, k1, o0, o1);
      }
      if (q == 0) {
        const int row = (ms >> 5) * 64 + p * 32 + (ms & 31);
        // TRANSPOSED layout [nt][m]: block writes contiguous 1KB runs
        cands[(size_t)nt * B_ROWS + (m0 + row)] = make_ulonglong2(k0, k1);
      }
    }
    __syncthreads();   // LDS reused by next pass
  }
}

// ---------------------------------------------------------------------------
// K5: per-row final. Merge 391 packed tile candidate pairs -> global top-2
// indices (u64 compares only), then recompute d_pos / d_neg exactly in fp32
// from the original inputs. cands is [nt][m]: phase-A reads are 16B gathers
// at 64KB stride — line-amplified but L3-absorbed (25.7MB total).
// ---------------------------------------------------------------------------
__global__ __launch_bounds__(256)
void finalize_kernel(const float* __restrict__ input, const float* __restrict__ target,
                     const float* __restrict__ veclist, const ulonglong2* __restrict__ cands,
                     float* __restrict__ contrib) {
  const int b = blockIdx.x;
  const int t = threadIdx.x;
  __shared__ ulonglong2 wpair[4];
  __shared__ int sidx[2];
  __shared__ float red[4][7];
  __shared__ int reda[4];

  // phase A: global top-2 across tiles
  u64 k0 = 0, k1 = 0;
  for (int nt = t; nt < NTILES; nt += 256) {
    ulonglong2 c = cands[(size_t)nt * B_ROWS + b];
    kmerge(k0, k1, c.x, c.y);
  }
  #pragma unroll
  for (int d = 1; d < 64; d <<= 1) {
    u64 o0 = __shfl_xor(k0, d), o1 = __shfl_xor(k1, d);
    kmerge(k0, k1, o0, o1);
  }
  if ((t & 63) == 0) wpair[t >> 6] = make_ulonglong2(k0, k1);
  __syncthreads();
  if (t == 0) {
    u64 m0k = wpair[0].x, m1k = wpair[0].y;
    for (int wd = 1; wd < 4; ++wd) kmerge(m0k, m1k, wpair[wd].x, wpair[wd].y);
    sidx[0] = key_col(m0k);
    sidx[1] = key_col(m1k);
  }
  __syncthreads();
  const int idx0 = sidx[0], idx1 = sidx[1];

  // phase B: exact fp32 dot products / norms
  const float2* xin = (const float2*)(input  + (size_t)b * DIMS);
  const float2* xtg = (const float2*)(target + (size_t)b * DIMS);
  const float2* xv0 = (const float2*)(veclist + (size_t)idx0 * DIMS);
  const float2* xv1 = (const float2*)(veclist + (size_t)idx1 * DIMS);
  float2 xi = xin[t], tg = xtg[t], a0 = xv0[t], a1 = xv1[t];
  float s[7];
  s[0] = xi.x * xi.x + xi.y * xi.y;
  s[1] = tg.x * tg.x + tg.y * tg.y;
  s[2] = xi.x * tg.x + xi.y * tg.y;
  s[3] = a0.x * a0.x + a0.y * a0.y;
  s[4] = xi.x * a0.x + xi.y * a0.y;
  s[5] = a1.x * a1.x + a1.y * a1.y;
  s[6] = xi.x * a1.x + xi.y * a1.y;
  bool eq = (a0.x == tg.x) && (a0.y == tg.y);
  int weq = __all(eq);
  #pragma unroll
  for (int k = 0; k < 7; ++k)
    #pragma unroll
    for (int d = 1; d < 64; d <<= 1) s[k] += __shfl_xor(s[k], d);
  if ((t & 63) == 0) {
    #pragma unroll
    for (int k = 0; k < 7; ++k) red[t >> 6][k] = s[k];
    reda[t >> 6] = weq;
  }
  __syncthreads();
  if (t == 0) {
    float r[7];
    #pragma unroll
    for (int k = 0; k < 7; ++k)
      r[k] = red[0][k] + red[1][k] + red[2][k] + red[3][k];
    bool eq0 = reda[0] && reda[1] && reda[2] && reda[3];
    float na  = fmaxf(sqrtf(r[0]), EPSF);
    float ntg = fmaxf(sqrtf(r[1]), EPSF);
    float simp = r[2] / (na * ntg);
    float d_pos = sqrtf(fmaxf(2.0f * (1.0f - simp), 1e-12f));
    float nn = eq0 ? fmaxf(sqrtf(r[5]), EPSF) : fmaxf(sqrtf(r[3]), EPSF);
    float dn = eq0 ? r[6] : r[4];
    float simn = dn / (na * nn);
    float d_neg = sqrtf(fmaxf(2.0f * (1.0f - simn), 1e-12f));
    float margin = 0.5f + d_pos - d_neg;          // GAMMA + d_pos - d_neg
    contrib[b] = 2.0f * fmaxf(margin, 0.0f) * (1.0f / (float)B_ROWS);  // RANK=2
  }
}

// ---------------------------------------------------------------------------
// K6: sum 4096 per-row contributions -> out[0]. One block, no atomics.
// ---------------------------------------------------------------------------
__global__ __launch_bounds__(256)
void reduce_kernel(const float* __restrict__ contrib, float* __restrict__ out) {
  const int t = threadIdx.x;
  __shared__ float wsum[4];
  float s = 0.0f;
  for (int i = t; i < B_ROWS; i += 256) s += contrib[i];
  #pragma unroll
  for (int d = 1; d < 64; d <<= 1) s += __shfl_xor(s, d);
  if ((t & 63) == 0) wsum[t >> 6] = s;
  __syncthreads();
  if (t == 0) out[0] = wsum[0] + wsum[1] + wsum[2] + wsum[3];
}

// ---------------------------------------------------------------------------
// Workspace layout (bytes):
//   vnn  fp8 [50048][512]          @ 0          : 25,624,576  (row-major)
//   apk  fp8 packed A-fragments    @ 25,624,576 :  2,097,152  (2048 x 1KB recs)
//   cands ulonglong2 [392][4096]   @ 27,721,728 : 25,690,112  (TRANSPOSED)
//   contrib float [4096]           @ 53,411,840 :     16,384   (total ~53.4 MB)
// ---------------------------------------------------------------------------
extern "C" void kernel_launch(void* const* d_in, const int* in_sizes, int n_in,
                              void* d_out, int out_size, void* d_ws, size_t ws_size,
                              hipStream_t stream) {
  const float* input   = (const float*)d_in[0];
  const float* target  = (const float*)d_in[1];
  const float* veclist = (const float*)d_in[2];
  float* out = (float*)d_out;
  char* ws = (char*)d_ws;
  unsigned char* vnn = (unsigned char*)ws;
  unsigned char* apk = (unsigned char*)(ws + 25624576);
  ulonglong2* cands = (ulonglong2*)(ws + 27721728);
  float* contrib = (float*)(ws + 53411840);

  normalize_rows_kernel<<<4096, 256, 0, stream>>>(veclist, input, vnn, apk);
  gemm_top2_kernel<<<NT_VIRT * MTILES, 256, 0, stream>>>(apk, vnn, cands);
  finalize_kernel<<<B_ROWS, 256, 0, stream>>>(input, target, veclist, cands, contrib);
  reduce_kernel<<<1, 256, 0, stream>>>(contrib, out);
}